// Round 1
// baseline (694.077 us; speedup 1.0000x reference)
//
#include <hip/hip_runtime.h>
#include <math.h>

#define NB 8
#define NH 120
#define NW 160
#define HW (NH*NW)
#define NSEM 16
#define NCH 20
#define VR 100
#define NZ 80
#define ZLO 9
#define ZHI 35
#define NZS (ZHI-ZLO)
#define MD 240
#define NJ 18   // stored channels of agent_view/rotated: 0,1,4..19

__device__ __forceinline__ float clamp01(float v){ return fminf(fmaxf(v, 0.0f), 1.0f); }

// ---------------- pose + affine params ----------------
__global__ void pose_k(const float* __restrict__ pose_obs,
                       const float* __restrict__ poses_last,
                       float* __restrict__ out2, float* __restrict__ out3,
                       float* __restrict__ aux) {
    int b = threadIdx.x;
    if (b >= NB) return;
    const float D2R = 0.017453292519943295f;
    float th = poses_last[b*3+2] * D2R;
    float s = sinf(th), c = cosf(th);
    float ny = poses_last[b*3+1] + pose_obs[b*3+0]*s + pose_obs[b*3+1]*c;
    float nx = poses_last[b*3+0] + pose_obs[b*3+0]*c - pose_obs[b*3+1]*s;
    float nt = poses_last[b*3+2] + pose_obs[b*3+2]*57.29577951308232f;
    nt = fmodf(nt - 180.0f, 360.0f) + 180.0f;
    nt = fmodf(nt + 180.0f, 360.0f) - 180.0f;
    out2[b*3+0] = nx; out2[b*3+1] = ny; out2[b*3+2] = nt;
    out3[b*3+0] = nx; out3[b*3+1] = ny; out3[b*3+2] = nt;
    float stt = 90.0f - nt;
    float rad = stt * D2R;
    aux[b*4+0] = cosf(rad);
    aux[b*4+1] = sinf(rad);
    aux[b*4+2] = -(nx*100.0f/5.0f - 120.0f)/120.0f;  // st_xy[:,0]
    aux[b*4+3] = -(ny*100.0f/5.0f - 120.0f)/120.0f;  // st_xy[:,1]
}

// ---------------- trilinear splat ----------------
// vox0: [b][z][y][x]  (ch 0, all z)   voxS: [b][c][z-ZLO][y][x]  (ch 1..16, slab only)
__global__ void splat_k(const float* __restrict__ obs,
                        float* __restrict__ vox0, float* __restrict__ voxS,
                        float fl) {
    int t = blockIdx.x*blockDim.x + threadIdx.x;
    if (t >= NB*HW) return;
    int b = t / HW, p = t % HW;
    int h = p / NW, w = p % NW;
    const float* ob = obs + (size_t)b*NCH*HW;
    float d = ob[3*HW + p];
    float X = ((float)w - 79.5f) * d / fl;
    float Z = ((float)(119 - h) - 59.5f) * d / fl;
    float pcx = X + 250.0f;
    float pcy = d;
    float pcz = Z + 88.0f;
    float posx = ((pcx/5.0f - 50.0f)/100.0f*2.0f)*50.0f + 50.0f;
    float posy = ((pcy/5.0f - 50.0f)/100.0f*2.0f)*50.0f + 50.0f;
    float posz = ((pcz/5.0f - 32.0f)/80.0f*2.0f)*40.0f + 40.0f;

    float wx[2], wy[2], wz[2]; int xi[2], yi[2], zi[2];
    float f;
    f = floorf(posx);
    #pragma unroll
    for (int i = 0; i < 2; i++) {
        float pi = f + (float)i; bool s = (pi > 0.0f) && (pi < 100.0f);
        wx[i] = s ? (1.0f - fabsf(posx - pi)) : 0.0f; xi[i] = s ? (int)pi : 0;
    }
    f = floorf(posy);
    #pragma unroll
    for (int i = 0; i < 2; i++) {
        float pi = f + (float)i; bool s = (pi > 0.0f) && (pi < 100.0f);
        wy[i] = s ? (1.0f - fabsf(posy - pi)) : 0.0f; yi[i] = s ? (int)pi : 0;
    }
    f = floorf(posz);
    #pragma unroll
    for (int i = 0; i < 2; i++) {
        float pi = f + (float)i; bool s = (pi > 0.0f) && (pi < 80.0f);
        wz[i] = s ? (1.0f - fabsf(posz - pi)) : 0.0f; zi[i] = s ? (int)pi : 0;
    }

    float feat[NSEM];
    #pragma unroll
    for (int j = 0; j < NSEM; j++) feat[j] = ob[(4+j)*HW + p];

    #pragma unroll
    for (int cx = 0; cx < 2; cx++)
    #pragma unroll
    for (int cy = 0; cy < 2; cy++)
    #pragma unroll
    for (int cz = 0; cz < 2; cz++) {
        float w3 = (wx[cx]*wy[cy])*wz[cz];
        if (w3 == 0.0f) continue;
        int x = xi[cx], y = yi[cy], z = zi[cz];
        atomicAdd(&vox0[(((size_t)b*NZ + z)*VR + y)*VR + x], w3);
        if (z >= ZLO && z < ZHI) {
            size_t base = ((((size_t)b*NSEM)*NZS + (z-ZLO))*VR + y)*VR + x;
            #pragma unroll
            for (int j = 0; j < NSEM; j++)
                atomicAdd(&voxS[base + (size_t)j*NZS*VR*VR], feat[j]*w3);
        }
    }
}

// ---------------- round + height projections + clips ----------------
// proj: [b][j][y][x], j: 0=fp_map, 1=fp_exp, 2..17 = sem clip(sum/5)
__global__ void proj_k(const float* __restrict__ vox0, const float* __restrict__ voxS,
                       float* __restrict__ proj, float* __restrict__ out0) {
    int t = blockIdx.x*blockDim.x + threadIdx.x;
    if (t >= NB*VR*VR) return;
    int b = t / (VR*VR), r = t % (VR*VR);
    int y = r / VR, x = r % VR;
    float s_all = 0.0f, s_slab = 0.0f;
    for (int z = 0; z < NZ; z++) {
        float v = rintf(vox0[(((size_t)b*NZ + z)*VR + y)*VR + x]);
        s_all += v;
        if (z >= ZLO && z < ZHI) s_slab += v;
    }
    float fpm = clamp01(s_slab);  // MAP_THR = 1
    float fpe = clamp01(s_all);   // EXP_THR = 1
    out0[(size_t)b*VR*VR + r] = fpm;
    float* pb = proj + ((size_t)b*NJ)*VR*VR;
    pb[0*VR*VR + r] = fpm;
    pb[1*VR*VR + r] = fpe;
    for (int c = 0; c < NSEM; c++) {
        float s = 0.0f;
        for (int zs = 0; zs < NZS; zs++)
            s += rintf(voxS[((((size_t)b*NSEM + c)*NZS + zs)*VR + y)*VR + x]);
        pb[(2+c)*VR*VR + r] = clamp01(s/5.0f);  // CAT_THR = 5
    }
}

// ---------------- rotation resample (samples agent_view window directly) ----------------
__global__ void rot_k(const float* __restrict__ proj, const float* __restrict__ aux,
                      float* __restrict__ rot) {
    int t = blockIdx.x*blockDim.x + threadIdx.x;
    if (t >= NB*NJ*MD*MD) return;
    int X = t % MD; int rest = t / MD;
    int Y = rest % MD; rest /= MD;
    int j = rest % NJ; int b = rest / NJ;
    float ct = aux[b*4+0], st = aux[b*4+1];
    const float step = 2.0f/239.0f;
    float Xg = (X == MD-1) ? 1.0f : (-1.0f + (float)X*step);
    float Yg = (Y == MD-1) ? 1.0f : (-1.0f + (float)Y*step);
    float u = ct*Xg - st*Yg;
    float v = st*Xg + ct*Yg;
    float x = (u + 1.0f)*(float)(MD-1)/2.0f;
    float y = (v + 1.0f)*(float)(MD-1)/2.0f;
    float x0 = floorf(x), y0 = floorf(y);
    const float* pj = proj + ((size_t)b*NJ + j)*VR*VR;
    auto tap = [&](float ix, float iy, float w) -> float {
        if (iy >= 120.0f && iy < 220.0f && ix >= 70.0f && ix < 170.0f) {
            int yy = (int)iy - 120, xx = (int)ix - 70;
            return pj[yy*VR + xx] * w;
        }
        return 0.0f;
    };
    float acc = tap(x0,        y0,        (x0+1.0f-x)*(y0+1.0f-y));
    acc      += tap(x0+1.0f,   y0,        (x-x0)*(y0+1.0f-y));
    acc      += tap(x0,        y0+1.0f,   (x0+1.0f-x)*(y-y0));
    acc      += tap(x0+1.0f,   y0+1.0f,   (x-x0)*(y-y0));
    rot[t] = acc;
}

// ---------------- translation resample + max with maps_last ----------------
__global__ void trans_k(const float* __restrict__ rot, const float* __restrict__ aux,
                        const float* __restrict__ maps, float* __restrict__ out1) {
    int t = blockIdx.x*blockDim.x + threadIdx.x;
    if (t >= NB*NCH*MD*MD) return;
    int X = t % MD; int rest = t / MD;
    int Y = rest % MD; rest /= MD;
    int ch = rest % NCH; int b = rest / NCH;
    float m = maps[t];
    float res;
    if (ch == 2 || ch == 3) {
        res = fmaxf(m, 0.0f);   // translated is exactly zero there
    } else {
        int j = (ch < 2) ? ch : ch - 2;
        const float step = 2.0f/239.0f;
        float Xg = (X == MD-1) ? 1.0f : (-1.0f + (float)X*step);
        float Yg = (Y == MD-1) ? 1.0f : (-1.0f + (float)Y*step);
        float u = Xg + aux[b*4+2];
        float v = Yg + aux[b*4+3];
        float x = (u + 1.0f)*(float)(MD-1)/2.0f;
        float y = (v + 1.0f)*(float)(MD-1)/2.0f;
        float x0 = floorf(x), y0 = floorf(y);
        const float* rb = rot + ((size_t)b*NJ + j)*MD*MD;
        auto tap = [&](float ix, float iy, float w) -> float {
            if (ix >= 0.0f && ix < (float)MD && iy >= 0.0f && iy < (float)MD) {
                int yy = (int)iy, xx = (int)ix;
                return rb[yy*MD + xx] * w;
            }
            return 0.0f;
        };
        float acc = tap(x0,      y0,      (x0+1.0f-x)*(y0+1.0f-y));
        acc      += tap(x0+1.0f, y0,      (x-x0)*(y0+1.0f-y));
        acc      += tap(x0,      y0+1.0f, (x0+1.0f-x)*(y-y0));
        acc      += tap(x0+1.0f, y0+1.0f, (x-x0)*(y-y0));
        res = fmaxf(m, acc);
    }
    out1[t] = res;
}

extern "C" void kernel_launch(void* const* d_in, const int* in_sizes, int n_in,
                              void* d_out, int out_size, void* d_ws, size_t ws_size,
                              hipStream_t stream) {
    const float* obs        = (const float*)d_in[0];
    const float* pose_obs   = (const float*)d_in[1];
    const float* maps_last  = (const float*)d_in[2];
    const float* poses_last = (const float*)d_in[3];
    float* out  = (float*)d_out;
    float* out0 = out;                        // fp_map_pred: 8*1*100*100
    float* out1 = out + 80000;                // map_pred: 8*20*240*240
    float* out2 = out + 80000 + 9216000;      // poses
    float* out3 = out2 + 24;                  // poses (again)

    float* ws   = (float*)d_ws;
    float* vox0 = ws;                                   // 8*80*100*100      = 6,400,000
    float* voxS = ws + 6400000;                         // 8*16*26*100*100   = 33,280,000
    float* proj = ws + 6400000 + 33280000;              // 8*18*100*100      = 1,440,000
    float* rot  = ws + 6400000 + 33280000 + 1440000;    // 8*18*240*240      = 8,294,400
    float* aux  = ws + 6400000 + 33280000 + 1440000 + 8294400;  // 8*4

    const float FLf = (float)(80.0 / tan(39.5 * M_PI / 180.0));

    // zero only the voxel accumulators (everything else is fully overwritten)
    hipMemsetAsync(vox0, 0, (size_t)(6400000 + 33280000)*sizeof(float), stream);
    pose_k <<<1, 64, 0, stream>>>(pose_obs, poses_last, out2, out3, aux);
    splat_k<<<(NB*HW + 255)/256, 256, 0, stream>>>(obs, vox0, voxS, FLf);
    proj_k <<<(NB*VR*VR + 255)/256, 256, 0, stream>>>(vox0, voxS, proj, out0);
    rot_k  <<<(NB*NJ*MD*MD + 255)/256, 256, 0, stream>>>(proj, aux, rot);
    trans_k<<<(NB*NCH*MD*MD + 255)/256, 256, 0, stream>>>(rot, aux, maps_last, out1);
}

// Round 2
// 207.069 us; speedup vs baseline: 3.3519x; 3.3519x over previous
//
#include <hip/hip_runtime.h>
#include <math.h>

#define NB 8
#define NH 120
#define NW 160
#define HW (NH*NW)
#define NSEM 16
#define NCH 20
#define VR 100
#define NZ 80
#define ZLO 9
#define ZHI 35
#define NZS (ZHI-ZLO)
#define MD 240
#define NJ 18   // stored channels of agent_view/rotated: 0,1,4..19

__device__ __forceinline__ float clamp01(float v){ return fminf(fmaxf(v, 0.0f), 1.0f); }

// Shared coordinate/weight computation (exact replica of reference f32 math).
struct SplatCoord {
    float wx[2], wy[2], wz[2];
    int xi[2], yi[2], zi[2];
};
__device__ __forceinline__ void compute_coord(float d, int h, int w, float fl, SplatCoord& sc) {
    float X = ((float)w - 79.5f) * d / fl;
    float Z = ((float)(119 - h) - 59.5f) * d / fl;
    float pcx = X + 250.0f;
    float pcy = d;
    float pcz = Z + 88.0f;
    float posx = ((pcx/5.0f - 50.0f)/100.0f*2.0f)*50.0f + 50.0f;
    float posy = ((pcy/5.0f - 50.0f)/100.0f*2.0f)*50.0f + 50.0f;
    float posz = ((pcz/5.0f - 32.0f)/80.0f*2.0f)*40.0f + 40.0f;
    float f;
    f = floorf(posx);
    #pragma unroll
    for (int i = 0; i < 2; i++) {
        float pi = f + (float)i; bool s = (pi > 0.0f) && (pi < 100.0f);
        sc.wx[i] = s ? (1.0f - fabsf(posx - pi)) : 0.0f; sc.xi[i] = s ? (int)pi : 0;
    }
    f = floorf(posy);
    #pragma unroll
    for (int i = 0; i < 2; i++) {
        float pi = f + (float)i; bool s = (pi > 0.0f) && (pi < 100.0f);
        sc.wy[i] = s ? (1.0f - fabsf(posy - pi)) : 0.0f; sc.yi[i] = s ? (int)pi : 0;
    }
    f = floorf(posz);
    #pragma unroll
    for (int i = 0; i < 2; i++) {
        float pi = f + (float)i; bool s = (pi > 0.0f) && (pi < 80.0f);
        sc.wz[i] = s ? (1.0f - fabsf(posz - pi)) : 0.0f; sc.zi[i] = s ? (int)pi : 0;
    }
}

// ---------------- pose + affine params ----------------
__global__ void pose_k(const float* __restrict__ pose_obs,
                       const float* __restrict__ poses_last,
                       float* __restrict__ out2, float* __restrict__ out3,
                       float* __restrict__ aux) {
    int b = threadIdx.x;
    if (b >= NB) return;
    const float D2R = 0.017453292519943295f;
    float th = poses_last[b*3+2] * D2R;
    float s = sinf(th), c = cosf(th);
    float ny = poses_last[b*3+1] + pose_obs[b*3+0]*s + pose_obs[b*3+1]*c;
    float nx = poses_last[b*3+0] + pose_obs[b*3+0]*c - pose_obs[b*3+1]*s;
    float nt = poses_last[b*3+2] + pose_obs[b*3+2]*57.29577951308232f;
    nt = fmodf(nt - 180.0f, 360.0f) + 180.0f;
    nt = fmodf(nt + 180.0f, 360.0f) - 180.0f;
    out2[b*3+0] = nx; out2[b*3+1] = ny; out2[b*3+2] = nt;
    out3[b*3+0] = nx; out3[b*3+1] = ny; out3[b*3+2] = nt;
    float stt = 90.0f - nt;
    float rad = stt * D2R;
    aux[b*4+0] = cosf(rad);
    aux[b*4+1] = sinf(rad);
    aux[b*4+2] = -(nx*100.0f/5.0f - 120.0f)/120.0f;  // st_xy[:,0]
    aux[b*4+3] = -(ny*100.0f/5.0f - 120.0f)/120.0f;  // st_xy[:,1]
}

// ---------------- ch0 splat: thread per (pixel, corner) ----------------
// vox0: [b][z][y][x]
__global__ void splat0_k(const float* __restrict__ obs, float* __restrict__ vox0, float fl) {
    int t = blockIdx.x*blockDim.x + threadIdx.x;
    if (t >= NB*HW*8) return;
    int corner = t & 7; int pp = t >> 3;
    int b = pp / HW, p = pp % HW;
    int h = p / NW, w = p % NW;
    float d = obs[((size_t)b*NCH + 3)*HW + p];
    SplatCoord sc;
    compute_coord(d, h, w, fl, sc);
    int cx = corner & 1, cy = (corner >> 1) & 1, cz = corner >> 2;
    float w3 = (sc.wx[cx]*sc.wy[cy])*sc.wz[cz];
    if (w3 != 0.0f) {
        atomicAdd(&vox0[(((size_t)b*NZ + sc.zi[cz])*VR + sc.yi[cy])*VR + sc.xi[cx]], w3);
    }
}

// ---------------- sem splat: thread per (pixel, channel) ----------------
// voxS: [b][zs][y][x][c16]  (channel-innermost so a wave's 16 channel atomics
// share one 64B line per corner)
__global__ void splatS_k(const float* __restrict__ obs, float* __restrict__ voxS, float fl) {
    int t = blockIdx.x*blockDim.x + threadIdx.x;
    if (t >= NB*HW*NSEM) return;
    int c = t & 15; int pp = t >> 4;
    int b = pp / HW, p = pp % HW;
    int h = p / NW, w = p % NW;
    const float* ob = obs + (size_t)b*NCH*HW;
    float d = ob[3*HW + p];
    SplatCoord sc;
    compute_coord(d, h, w, fl, sc);
    float feat = ob[(4+c)*HW + p];
    #pragma unroll
    for (int cz = 0; cz < 2; cz++) {
        int z = sc.zi[cz];
        if (z < ZLO || z >= ZHI) continue;
        float wzv = sc.wz[cz];
        #pragma unroll
        for (int cx = 0; cx < 2; cx++)
        #pragma unroll
        for (int cy = 0; cy < 2; cy++) {
            float w3 = (sc.wx[cx]*sc.wy[cy])*wzv;
            if (w3 == 0.0f) continue;
            size_t addr = (((((size_t)b*NZS + (z-ZLO))*VR + sc.yi[cy])*VR + sc.xi[cx])<<4) + c;
            atomicAdd(&voxS[addr], feat*w3);
        }
    }
}

// ---------------- round + height projections + clips ----------------
// proj: [b][j][y][x], j: 0=fp_map, 1=fp_exp, 2..17 = sem clip(sum/5)
__global__ void proj_k(const float* __restrict__ vox0, const float* __restrict__ voxS,
                       float* __restrict__ proj, float* __restrict__ out0) {
    int t = blockIdx.x*blockDim.x + threadIdx.x;
    if (t >= NB*VR*VR) return;
    int b = t / (VR*VR), r = t % (VR*VR);
    float s_all = 0.0f, s_slab = 0.0f;
    #pragma unroll 8
    for (int z = 0; z < NZ; z++) {
        float v = rintf(vox0[((size_t)b*NZ + z)*(VR*VR) + r]);
        s_all += v;
        if (z >= ZLO && z < ZHI) s_slab += v;
    }
    float fpm = clamp01(s_slab);  // MAP_THR = 1
    float fpe = clamp01(s_all);   // EXP_THR = 1
    out0[(size_t)b*VR*VR + r] = fpm;
    float* pb = proj + ((size_t)b*NJ)*(VR*VR);
    pb[0*(VR*VR) + r] = fpm;
    pb[1*(VR*VR) + r] = fpe;
    float acc[NSEM];
    #pragma unroll
    for (int c = 0; c < NSEM; c++) acc[c] = 0.0f;
    for (int zs = 0; zs < NZS; zs++) {
        const float* base = voxS + ((((size_t)b*NZS + zs)*(VR*VR) + r)<<4);
        #pragma unroll
        for (int q = 0; q < 4; q++) {
            float4 v = *reinterpret_cast<const float4*>(base + q*4);
            acc[q*4+0] += rintf(v.x);
            acc[q*4+1] += rintf(v.y);
            acc[q*4+2] += rintf(v.z);
            acc[q*4+3] += rintf(v.w);
        }
    }
    #pragma unroll
    for (int c = 0; c < NSEM; c++)
        pb[(2+c)*(VR*VR) + r] = clamp01(acc[c]/5.0f);  // CAT_THR = 5
}

// ---------------- rotation resample (samples agent_view window directly) ----------------
__global__ void rot_k(const float* __restrict__ proj, const float* __restrict__ aux,
                      float* __restrict__ rot) {
    int t = blockIdx.x*blockDim.x + threadIdx.x;
    if (t >= NB*NJ*MD*MD) return;
    int X = t % MD; int rest = t / MD;
    int Y = rest % MD; rest /= MD;
    int j = rest % NJ; int b = rest / NJ;
    float ct = aux[b*4+0], st = aux[b*4+1];
    const float step = 2.0f/239.0f;
    float Xg = (X == MD-1) ? 1.0f : (-1.0f + (float)X*step);
    float Yg = (Y == MD-1) ? 1.0f : (-1.0f + (float)Y*step);
    float u = ct*Xg - st*Yg;
    float v = st*Xg + ct*Yg;
    float x = (u + 1.0f)*(float)(MD-1)/2.0f;
    float y = (v + 1.0f)*(float)(MD-1)/2.0f;
    float x0 = floorf(x), y0 = floorf(y);
    const float* pj = proj + ((size_t)b*NJ + j)*(VR*VR);
    auto tap = [&](float ix, float iy, float w) -> float {
        if (iy >= 120.0f && iy < 220.0f && ix >= 70.0f && ix < 170.0f) {
            int yy = (int)iy - 120, xx = (int)ix - 70;
            return pj[yy*VR + xx] * w;
        }
        return 0.0f;
    };
    float acc = tap(x0,        y0,        (x0+1.0f-x)*(y0+1.0f-y));
    acc      += tap(x0+1.0f,   y0,        (x-x0)*(y0+1.0f-y));
    acc      += tap(x0,        y0+1.0f,   (x0+1.0f-x)*(y-y0));
    acc      += tap(x0+1.0f,   y0+1.0f,   (x-x0)*(y-y0));
    rot[t] = acc;
}

// ---------------- translation resample + max with maps_last ----------------
__global__ void trans_k(const float* __restrict__ rot, const float* __restrict__ aux,
                        const float* __restrict__ maps, float* __restrict__ out1) {
    int t = blockIdx.x*blockDim.x + threadIdx.x;
    if (t >= NB*NCH*MD*MD) return;
    int X = t % MD; int rest = t / MD;
    int Y = rest % MD; rest /= MD;
    int ch = rest % NCH; int b = rest / NCH;
    float m = maps[t];
    float res;
    if (ch == 2 || ch == 3) {
        res = fmaxf(m, 0.0f);   // translated is exactly zero there
    } else {
        int j = (ch < 2) ? ch : ch - 2;
        const float step = 2.0f/239.0f;
        float Xg = (X == MD-1) ? 1.0f : (-1.0f + (float)X*step);
        float Yg = (Y == MD-1) ? 1.0f : (-1.0f + (float)Y*step);
        float u = Xg + aux[b*4+2];
        float v = Yg + aux[b*4+3];
        float x = (u + 1.0f)*(float)(MD-1)/2.0f;
        float y = (v + 1.0f)*(float)(MD-1)/2.0f;
        float x0 = floorf(x), y0 = floorf(y);
        const float* rb = rot + ((size_t)b*NJ + j)*(MD*MD);
        auto tap = [&](float ix, float iy, float w) -> float {
            if (ix >= 0.0f && ix < (float)MD && iy >= 0.0f && iy < (float)MD) {
                int yy = (int)iy, xx = (int)ix;
                return rb[yy*MD + xx] * w;
            }
            return 0.0f;
        };
        float acc = tap(x0,      y0,      (x0+1.0f-x)*(y0+1.0f-y));
        acc      += tap(x0+1.0f, y0,      (x-x0)*(y0+1.0f-y));
        acc      += tap(x0,      y0+1.0f, (x0+1.0f-x)*(y-y0));
        acc      += tap(x0+1.0f, y0+1.0f, (x-x0)*(y-y0));
        res = fmaxf(m, acc);
    }
    out1[t] = res;
}

extern "C" void kernel_launch(void* const* d_in, const int* in_sizes, int n_in,
                              void* d_out, int out_size, void* d_ws, size_t ws_size,
                              hipStream_t stream) {
    const float* obs        = (const float*)d_in[0];
    const float* pose_obs   = (const float*)d_in[1];
    const float* maps_last  = (const float*)d_in[2];
    const float* poses_last = (const float*)d_in[3];
    float* out  = (float*)d_out;
    float* out0 = out;                        // fp_map_pred: 8*1*100*100
    float* out1 = out + 80000;                // map_pred: 8*20*240*240
    float* out2 = out + 80000 + 9216000;      // poses
    float* out3 = out2 + 24;                  // poses (again)

    float* ws   = (float*)d_ws;
    float* vox0 = ws;                                   // 8*80*100*100          = 6,400,000
    float* voxS = ws + 6400000;                         // 8*26*100*100*16       = 33,280,000
    float* proj = ws + 6400000 + 33280000;              // 8*18*100*100          = 1,440,000
    float* rot  = ws + 6400000 + 33280000 + 1440000;    // 8*18*240*240          = 8,294,400
    float* aux  = ws + 6400000 + 33280000 + 1440000 + 8294400;  // 8*4

    const float FLf = (float)(80.0 / tan(39.5 * M_PI / 180.0));

    // zero only the voxel accumulators (everything else is fully overwritten)
    hipMemsetAsync(vox0, 0, (size_t)(6400000 + 33280000)*sizeof(float), stream);
    pose_k  <<<1, 64, 0, stream>>>(pose_obs, poses_last, out2, out3, aux);
    splat0_k<<<(NB*HW*8 + 255)/256, 256, 0, stream>>>(obs, vox0, FLf);
    splatS_k<<<(NB*HW*NSEM + 255)/256, 256, 0, stream>>>(obs, voxS, FLf);
    proj_k  <<<(NB*VR*VR + 255)/256, 256, 0, stream>>>(vox0, voxS, proj, out0);
    rot_k   <<<(NB*NJ*MD*MD + 255)/256, 256, 0, stream>>>(proj, aux, rot);
    trans_k <<<(NB*NCH*MD*MD + 255)/256, 256, 0, stream>>>(rot, aux, maps_last, out1);
}

// Round 3
// 191.252 us; speedup vs baseline: 3.6291x; 1.0827x over previous
//
#include <hip/hip_runtime.h>
#include <math.h>

#define NB 8
#define NH 120
#define NW 160
#define HW (NH*NW)
#define NSEM 16
#define NCH 20
#define VR 100
#define NZ 80
#define ZLO 9
#define ZHI 35
#define NZS (ZHI-ZLO)
#define MD 240
#define NJ 18   // stored channels of agent_view/rotated: 0,1,4..19
#define YW 64   // y-window rows actually touchable by the splat (posy = d/5 in [10,70])
#define YOFF 8

__device__ __forceinline__ float clamp01(float v){ return fminf(fmaxf(v, 0.0f), 1.0f); }

// Shared coordinate/weight computation (exact replica of reference f32 math).
struct SplatCoord {
    float wx[2], wy[2], wz[2];
    int xi[2], yi[2], zi[2];
};
__device__ __forceinline__ void compute_coord(float d, int h, int w, float fl, SplatCoord& sc) {
    float X = ((float)w - 79.5f) * d / fl;
    float Z = ((float)(119 - h) - 59.5f) * d / fl;
    float pcx = X + 250.0f;
    float pcy = d;
    float pcz = Z + 88.0f;
    float posx = ((pcx/5.0f - 50.0f)/100.0f*2.0f)*50.0f + 50.0f;
    float posy = ((pcy/5.0f - 50.0f)/100.0f*2.0f)*50.0f + 50.0f;
    float posz = ((pcz/5.0f - 32.0f)/80.0f*2.0f)*40.0f + 40.0f;
    float f;
    f = floorf(posx);
    #pragma unroll
    for (int i = 0; i < 2; i++) {
        float pi = f + (float)i; bool s = (pi > 0.0f) && (pi < 100.0f);
        sc.wx[i] = s ? (1.0f - fabsf(posx - pi)) : 0.0f; sc.xi[i] = s ? (int)pi : 0;
    }
    f = floorf(posy);
    #pragma unroll
    for (int i = 0; i < 2; i++) {
        float pi = f + (float)i; bool s = (pi > 0.0f) && (pi < 100.0f);
        sc.wy[i] = s ? (1.0f - fabsf(posy - pi)) : 0.0f; sc.yi[i] = s ? (int)pi : 0;
    }
    f = floorf(posz);
    #pragma unroll
    for (int i = 0; i < 2; i++) {
        float pi = f + (float)i; bool s = (pi > 0.0f) && (pi < 80.0f);
        sc.wz[i] = s ? (1.0f - fabsf(posz - pi)) : 0.0f; sc.zi[i] = s ? (int)pi : 0;
    }
}

// ---------------- pose + affine params ----------------
__global__ void pose_k(const float* __restrict__ pose_obs,
                       const float* __restrict__ poses_last,
                       float* __restrict__ out2, float* __restrict__ out3,
                       float* __restrict__ aux) {
    int b = threadIdx.x;
    if (b >= NB) return;
    const float D2R = 0.017453292519943295f;
    float th = poses_last[b*3+2] * D2R;
    float s = sinf(th), c = cosf(th);
    float ny = poses_last[b*3+1] + pose_obs[b*3+0]*s + pose_obs[b*3+1]*c;
    float nx = poses_last[b*3+0] + pose_obs[b*3+0]*c - pose_obs[b*3+1]*s;
    float nt = poses_last[b*3+2] + pose_obs[b*3+2]*57.29577951308232f;
    nt = fmodf(nt - 180.0f, 360.0f) + 180.0f;
    nt = fmodf(nt + 180.0f, 360.0f) - 180.0f;
    out2[b*3+0] = nx; out2[b*3+1] = ny; out2[b*3+2] = nt;
    out3[b*3+0] = nx; out3[b*3+1] = ny; out3[b*3+2] = nt;
    float stt = 90.0f - nt;
    float rad = stt * D2R;
    aux[b*4+0] = cosf(rad);
    aux[b*4+1] = sinf(rad);
    aux[b*4+2] = -(nx*100.0f/5.0f - 120.0f)/120.0f;  // st_xy[:,0]
    aux[b*4+3] = -(ny*100.0f/5.0f - 120.0f)/120.0f;  // st_xy[:,1]
}

// ---------------- ch0 splat: thread per (pixel, corner) ----------------
// vox0: [b][z][yw][x]
__global__ void splat0_k(const float* __restrict__ obs, float* __restrict__ vox0, float fl) {
    int t = blockIdx.x*blockDim.x + threadIdx.x;
    if (t >= NB*HW*8) return;
    int corner = t & 7; int pp = t >> 3;
    int b = pp / HW, p = pp % HW;
    int h = p / NW, w = p % NW;
    float d = obs[((size_t)b*NCH + 3)*HW + p];
    SplatCoord sc;
    compute_coord(d, h, w, fl, sc);
    int cx = corner & 1, cy = (corner >> 1) & 1, cz = corner >> 2;
    float w3 = (sc.wx[cx]*sc.wy[cy])*sc.wz[cz];
    unsigned ywi = (unsigned)(sc.yi[cy] - YOFF);
    if (w3 != 0.0f && ywi < YW) {
        atomicAdd(&vox0[(((size_t)b*NZ + sc.zi[cz])*YW + ywi)*VR + sc.xi[cx]], w3);
    }
}

// ---------------- sem splat: thread per (pixel, channel) ----------------
// voxS: [b][zs][yw][x][c16]  (channel-innermost so a wave's 16 channel atomics
// share one 64B line per corner)
__global__ void splatS_k(const float* __restrict__ obs, float* __restrict__ voxS, float fl) {
    int t = blockIdx.x*blockDim.x + threadIdx.x;
    if (t >= NB*HW*NSEM) return;
    int c = t & 15; int pp = t >> 4;
    int b = pp / HW, p = pp % HW;
    int h = p / NW, w = p % NW;
    const float* ob = obs + (size_t)b*NCH*HW;
    float d = ob[3*HW + p];
    SplatCoord sc;
    compute_coord(d, h, w, fl, sc);
    float feat = ob[(4+c)*HW + p];
    #pragma unroll
    for (int cz = 0; cz < 2; cz++) {
        int z = sc.zi[cz];
        if (z < ZLO || z >= ZHI) continue;
        float wzv = sc.wz[cz];
        #pragma unroll
        for (int cx = 0; cx < 2; cx++)
        #pragma unroll
        for (int cy = 0; cy < 2; cy++) {
            float w3 = (sc.wx[cx]*sc.wy[cy])*wzv;
            unsigned ywi = (unsigned)(sc.yi[cy] - YOFF);
            if (w3 == 0.0f || ywi >= YW) continue;
            size_t addr = (((((size_t)b*NZS + (z-ZLO))*YW + ywi)*VR + sc.xi[cx])<<4) + c;
            atomicAdd(&voxS[addr], feat*w3);
        }
    }
}

// ---------------- round + height projections (ch0) ----------------
// proj: [b][j][y][x], j: 0=fp_map, 1=fp_exp, 2..17 = sem clip(sum/5)
__global__ void proj_main_k(const float* __restrict__ vox0,
                            float* __restrict__ proj, float* __restrict__ out0) {
    int t = blockIdx.x*blockDim.x + threadIdx.x;
    if (t >= NB*VR*VR) return;
    int b = t / (VR*VR), r = t % (VR*VR);
    int yy = r / VR;
    float* pb = proj + (size_t)b*NJ*(VR*VR);
    if (yy < YOFF || yy >= YOFF+YW) {
        out0[(size_t)b*(VR*VR) + r] = 0.0f;
        pb[r] = 0.0f; pb[(VR*VR) + r] = 0.0f;
        return;
    }
    int rw = (yy - YOFF)*VR + (r % VR);
    float s_all = 0.0f, s_slab = 0.0f;
    #pragma unroll 16
    for (int z = 0; z < NZ; z++) {
        float v = rintf(vox0[((size_t)b*NZ + z)*(YW*VR) + rw]);
        s_all += v;
        if (z >= ZLO && z < ZHI) s_slab += v;
    }
    float fpm = clamp01(s_slab);  // MAP_THR = 1
    float fpe = clamp01(s_all);   // EXP_THR = 1
    out0[(size_t)b*(VR*VR) + r] = fpm;
    pb[r] = fpm;
    pb[(VR*VR) + r] = fpe;
}

// ---------------- sem projection: thread per (b, pixel, channel-quad) ----------------
__global__ void proj_sem_k(const float* __restrict__ voxS, float* __restrict__ proj) {
    int t = blockIdx.x*blockDim.x + threadIdx.x;
    if (t >= NB*VR*VR*4) return;
    int q = t & 3; int rr = t >> 2;
    int b = rr / (VR*VR), r = rr % (VR*VR);
    int yy = r / VR;
    float* dst = proj + (size_t)b*NJ*(VR*VR) + (size_t)(2 + q*4)*(VR*VR) + r;
    if (yy < YOFF || yy >= YOFF+YW) {
        dst[0] = 0.0f; dst[VR*VR] = 0.0f; dst[2*VR*VR] = 0.0f; dst[3*VR*VR] = 0.0f;
        return;
    }
    int rw = (yy - YOFF)*VR + (r % VR);
    float a0 = 0.0f, a1 = 0.0f, a2 = 0.0f, a3 = 0.0f;
    #pragma unroll 13
    for (int zs = 0; zs < NZS; zs++) {
        const float4 v = *reinterpret_cast<const float4*>(
            voxS + ((((size_t)b*NZS + zs)*(YW*VR) + rw)<<4) + q*4);
        a0 += rintf(v.x); a1 += rintf(v.y); a2 += rintf(v.z); a3 += rintf(v.w);
    }
    dst[0]         = clamp01(a0/5.0f);   // CAT_THR = 5
    dst[VR*VR]     = clamp01(a1/5.0f);
    dst[2*(VR*VR)] = clamp01(a2/5.0f);
    dst[3*(VR*VR)] = clamp01(a3/5.0f);
}

// ---------------- fused rotate+translate resample + max with maps_last ----------------
// translated(X,Y) = sum of 4 integer-pixel taps of rotated, and rotated at an
// integer pixel is itself a 4-tap bilinear of proj -> exact composition, <=16 proj taps.
__global__ void rottrans_k(const float* __restrict__ proj, const float* __restrict__ aux,
                           const float* __restrict__ maps, float* __restrict__ out1) {
    int t = blockIdx.x*blockDim.x + threadIdx.x;
    if (t >= NB*NCH*MD*MD) return;
    int X = t % MD; int rest = t / MD;
    int Y = rest % MD; rest /= MD;
    int ch = rest % NCH; int b = rest / NCH;
    float m = maps[t];
    if (ch == 2 || ch == 3) { out1[t] = fmaxf(m, 0.0f); return; }
    int j = (ch < 2) ? ch : ch - 2;
    float ct = aux[b*4+0], st = aux[b*4+1];
    float tx = aux[b*4+2], ty = aux[b*4+3];
    const float step = 2.0f/239.0f;
    float Xg = (X == MD-1) ? 1.0f : (-1.0f + (float)X*step);
    float Yg = (Y == MD-1) ? 1.0f : (-1.0f + (float)Y*step);
    float x = (Xg + tx + 1.0f)*119.5f;
    float y = (Yg + ty + 1.0f)*119.5f;
    float x0 = floorf(x), y0 = floorf(y);
    const float* pj = proj + ((size_t)b*NJ + j)*(VR*VR);

    auto rotval = [&](int Xi, int Yi) -> float {
        float Xg2 = (Xi == MD-1) ? 1.0f : (-1.0f + (float)Xi*step);
        float Yg2 = (Yi == MD-1) ? 1.0f : (-1.0f + (float)Yi*step);
        float u = ct*Xg2 - st*Yg2;
        float v = st*Xg2 + ct*Yg2;
        float x2 = (u + 1.0f)*119.5f;
        float y2 = (v + 1.0f)*119.5f;
        float x20 = floorf(x2), y20 = floorf(y2);
        auto tap2 = [&](float ix, float iy, float w) -> float {
            if (iy >= 120.0f && iy < 220.0f && ix >= 70.0f && ix < 170.0f) {
                int yy = (int)iy - 120, xx = (int)ix - 70;
                return pj[yy*VR + xx] * w;
            }
            return 0.0f;
        };
        float a = tap2(x20,      y20,      (x20+1.0f-x2)*(y20+1.0f-y2));
        a      += tap2(x20+1.0f, y20,      (x2-x20)*(y20+1.0f-y2));
        a      += tap2(x20,      y20+1.0f, (x20+1.0f-x2)*(y2-y20));
        a      += tap2(x20+1.0f, y20+1.0f, (x2-x20)*(y2-y20));
        return a;
    };
    auto tap = [&](float ix, float iy, float w) -> float {
        if (ix >= 0.0f && ix < 240.0f && iy >= 0.0f && iy < 240.0f && w != 0.0f)
            return rotval((int)ix, (int)iy) * w;
        return 0.0f;
    };
    float acc = tap(x0,      y0,      (x0+1.0f-x)*(y0+1.0f-y));
    acc      += tap(x0+1.0f, y0,      (x-x0)*(y0+1.0f-y));
    acc      += tap(x0,      y0+1.0f, (x0+1.0f-x)*(y-y0));
    acc      += tap(x0+1.0f, y0+1.0f, (x-x0)*(y-y0));
    out1[t] = fmaxf(m, acc);
}

extern "C" void kernel_launch(void* const* d_in, const int* in_sizes, int n_in,
                              void* d_out, int out_size, void* d_ws, size_t ws_size,
                              hipStream_t stream) {
    const float* obs        = (const float*)d_in[0];
    const float* pose_obs   = (const float*)d_in[1];
    const float* maps_last  = (const float*)d_in[2];
    const float* poses_last = (const float*)d_in[3];
    float* out  = (float*)d_out;
    float* out0 = out;                        // fp_map_pred: 8*1*100*100
    float* out1 = out + 80000;                // map_pred: 8*20*240*240
    float* out2 = out + 80000 + 9216000;      // poses
    float* out3 = out2 + 24;                  // poses (again)

    float* ws   = (float*)d_ws;
    float* vox0 = ws;                         // 8*80*64*100          = 4,096,000
    float* voxS = ws + 4096000;               // 8*26*64*100*16       = 21,299,200
    float* proj = ws + 4096000 + 21299200;    // 8*18*100*100         = 1,440,000
    float* aux  = ws + 4096000 + 21299200 + 1440000;  // 8*4

    const float FLf = (float)(80.0 / tan(39.5 * M_PI / 180.0));

    // zero only the voxel accumulators (everything else is fully overwritten)
    hipMemsetAsync(vox0, 0, (size_t)(4096000 + 21299200)*sizeof(float), stream);
    pose_k     <<<1, 64, 0, stream>>>(pose_obs, poses_last, out2, out3, aux);
    splat0_k   <<<(NB*HW*8 + 255)/256, 256, 0, stream>>>(obs, vox0, FLf);
    splatS_k   <<<(NB*HW*NSEM + 255)/256, 256, 0, stream>>>(obs, voxS, FLf);
    proj_main_k<<<(NB*VR*VR + 255)/256, 256, 0, stream>>>(vox0, proj, out0);
    proj_sem_k <<<(NB*VR*VR*4 + 255)/256, 256, 0, stream>>>(voxS, proj);
    rottrans_k <<<(NB*NCH*MD*MD + 255)/256, 256, 0, stream>>>(proj, aux, maps_last, out1);
}

// Round 4
// 148.300 us; speedup vs baseline: 4.6802x; 1.2896x over previous
//
#include <hip/hip_runtime.h>
#include <math.h>

#define NB 8
#define NH 120
#define NW 160
#define HW (NH*NW)
#define NSEM 16
#define NCH 20
#define VR 100
#define NZ 80
#define ZLO 9
#define ZHI 35
#define NZS (ZHI-ZLO)
#define MD 240
#define PC 20   // proj channel stride (channel-innermost, slot == output channel, 2/3 unused)
#define YW 64   // y-window rows actually touchable by the splat (posy = d/5 in [10,70])
#define YOFF 8

__device__ __forceinline__ float clamp01(float v){ return fminf(fmaxf(v, 0.0f), 1.0f); }

// Shared coordinate/weight computation (exact replica of reference f32 math).
struct SplatCoord {
    float wx[2], wy[2], wz[2];
    int xi[2], yi[2], zi[2];
};
__device__ __forceinline__ void compute_coord(float d, int h, int w, float fl, SplatCoord& sc) {
    float X = ((float)w - 79.5f) * d / fl;
    float Z = ((float)(119 - h) - 59.5f) * d / fl;
    float pcx = X + 250.0f;
    float pcy = d;
    float pcz = Z + 88.0f;
    float posx = ((pcx/5.0f - 50.0f)/100.0f*2.0f)*50.0f + 50.0f;
    float posy = ((pcy/5.0f - 50.0f)/100.0f*2.0f)*50.0f + 50.0f;
    float posz = ((pcz/5.0f - 32.0f)/80.0f*2.0f)*40.0f + 40.0f;
    float f;
    f = floorf(posx);
    #pragma unroll
    for (int i = 0; i < 2; i++) {
        float pi = f + (float)i; bool s = (pi > 0.0f) && (pi < 100.0f);
        sc.wx[i] = s ? (1.0f - fabsf(posx - pi)) : 0.0f; sc.xi[i] = s ? (int)pi : 0;
    }
    f = floorf(posy);
    #pragma unroll
    for (int i = 0; i < 2; i++) {
        float pi = f + (float)i; bool s = (pi > 0.0f) && (pi < 100.0f);
        sc.wy[i] = s ? (1.0f - fabsf(posy - pi)) : 0.0f; sc.yi[i] = s ? (int)pi : 0;
    }
    f = floorf(posz);
    #pragma unroll
    for (int i = 0; i < 2; i++) {
        float pi = f + (float)i; bool s = (pi > 0.0f) && (pi < 80.0f);
        sc.wz[i] = s ? (1.0f - fabsf(posz - pi)) : 0.0f; sc.zi[i] = s ? (int)pi : 0;
    }
}

// ---------------- pose + affine params ----------------
__global__ void pose_k(const float* __restrict__ pose_obs,
                       const float* __restrict__ poses_last,
                       float* __restrict__ out2, float* __restrict__ out3,
                       float* __restrict__ aux) {
    int b = threadIdx.x;
    if (b >= NB) return;
    const float D2R = 0.017453292519943295f;
    float th = poses_last[b*3+2] * D2R;
    float s = sinf(th), c = cosf(th);
    float ny = poses_last[b*3+1] + pose_obs[b*3+0]*s + pose_obs[b*3+1]*c;
    float nx = poses_last[b*3+0] + pose_obs[b*3+0]*c - pose_obs[b*3+1]*s;
    float nt = poses_last[b*3+2] + pose_obs[b*3+2]*57.29577951308232f;
    nt = fmodf(nt - 180.0f, 360.0f) + 180.0f;
    nt = fmodf(nt + 180.0f, 360.0f) - 180.0f;
    out2[b*3+0] = nx; out2[b*3+1] = ny; out2[b*3+2] = nt;
    out3[b*3+0] = nx; out3[b*3+1] = ny; out3[b*3+2] = nt;
    float stt = 90.0f - nt;
    float rad = stt * D2R;
    aux[b*4+0] = cosf(rad);
    aux[b*4+1] = sinf(rad);
    aux[b*4+2] = -(nx*100.0f/5.0f - 120.0f)/120.0f;  // st_xy[:,0]
    aux[b*4+3] = -(ny*100.0f/5.0f - 120.0f)/120.0f;  // st_xy[:,1]
}

// ---------------- ch0 splat: thread per (pixel, corner) ----------------
// vox0: [b][z][yw][x]
__global__ void splat0_k(const float* __restrict__ obs, float* __restrict__ vox0, float fl) {
    int t = blockIdx.x*blockDim.x + threadIdx.x;
    if (t >= NB*HW*8) return;
    int corner = t & 7; int pp = t >> 3;
    int b = pp / HW, p = pp % HW;
    int h = p / NW, w = p % NW;
    float d = obs[((size_t)b*NCH + 3)*HW + p];
    SplatCoord sc;
    compute_coord(d, h, w, fl, sc);
    int cx = corner & 1, cy = (corner >> 1) & 1, cz = corner >> 2;
    float w3 = (sc.wx[cx]*sc.wy[cy])*sc.wz[cz];
    unsigned ywi = (unsigned)(sc.yi[cy] - YOFF);
    if (w3 != 0.0f && ywi < YW) {
        atomicAdd(&vox0[(((size_t)b*NZ + sc.zi[cz])*YW + ywi)*VR + sc.xi[cx]], w3);
    }
}

// ---------------- sem splat: thread per (pixel, channel) ----------------
// voxS: [b][zs][yw][x][c16]  (channel-innermost so a wave's 16 channel atomics
// share one 64B line per corner)
__global__ void splatS_k(const float* __restrict__ obs, float* __restrict__ voxS, float fl) {
    int t = blockIdx.x*blockDim.x + threadIdx.x;
    if (t >= NB*HW*NSEM) return;
    int c = t & 15; int pp = t >> 4;
    int b = pp / HW, p = pp % HW;
    int h = p / NW, w = p % NW;
    const float* ob = obs + (size_t)b*NCH*HW;
    float d = ob[3*HW + p];
    SplatCoord sc;
    compute_coord(d, h, w, fl, sc);
    float feat = ob[(4+c)*HW + p];
    #pragma unroll
    for (int cz = 0; cz < 2; cz++) {
        int z = sc.zi[cz];
        if (z < ZLO || z >= ZHI) continue;
        float wzv = sc.wz[cz];
        #pragma unroll
        for (int cx = 0; cx < 2; cx++)
        #pragma unroll
        for (int cy = 0; cy < 2; cy++) {
            float w3 = (sc.wx[cx]*sc.wy[cy])*wzv;
            unsigned ywi = (unsigned)(sc.yi[cy] - YOFF);
            if (w3 == 0.0f || ywi >= YW) continue;
            size_t addr = (((((size_t)b*NZS + (z-ZLO))*YW + ywi)*VR + sc.xi[cx])<<4) + c;
            atomicAdd(&voxS[addr], feat*w3);
        }
    }
}

// ---------------- round + height projections (ch0) ----------------
// proj layout: [b][pix][PC], slot == output channel (0,1 here; 4..19 sem; 2,3 unused)
__global__ void proj_main_k(const float* __restrict__ vox0,
                            float* __restrict__ proj, float* __restrict__ out0) {
    int t = blockIdx.x*blockDim.x + threadIdx.x;
    if (t >= NB*VR*VR) return;
    int b = t / (VR*VR), r = t % (VR*VR);
    int yy = r / VR;
    float* pb = proj + ((size_t)b*(VR*VR) + r)*PC;
    if (yy < YOFF || yy >= YOFF+YW) {
        out0[(size_t)b*(VR*VR) + r] = 0.0f;
        *reinterpret_cast<float2*>(pb) = make_float2(0.0f, 0.0f);
        return;
    }
    int rw = (yy - YOFF)*VR + (r % VR);
    float s_all = 0.0f, s_slab = 0.0f;
    #pragma unroll 16
    for (int z = 0; z < NZ; z++) {
        float v = rintf(vox0[((size_t)b*NZ + z)*(YW*VR) + rw]);
        s_all += v;
        if (z >= ZLO && z < ZHI) s_slab += v;
    }
    float fpm = clamp01(s_slab);  // MAP_THR = 1
    float fpe = clamp01(s_all);   // EXP_THR = 1
    out0[(size_t)b*(VR*VR) + r] = fpm;
    *reinterpret_cast<float2*>(pb) = make_float2(fpm, fpe);
}

// ---------------- sem projection: thread per (b, pixel, channel-quad) ----------------
__global__ void proj_sem_k(const float* __restrict__ voxS, float* __restrict__ proj) {
    int t = blockIdx.x*blockDim.x + threadIdx.x;
    if (t >= NB*VR*VR*4) return;
    int q = t & 3; int rr = t >> 2;
    int b = rr / (VR*VR), r = rr % (VR*VR);
    int yy = r / VR;
    float* dst = proj + ((size_t)b*(VR*VR) + r)*PC + 4 + q*4;  // 16B aligned
    if (yy < YOFF || yy >= YOFF+YW) {
        *reinterpret_cast<float4*>(dst) = make_float4(0.0f, 0.0f, 0.0f, 0.0f);
        return;
    }
    int rw = (yy - YOFF)*VR + (r % VR);
    float a0 = 0.0f, a1 = 0.0f, a2 = 0.0f, a3 = 0.0f;
    #pragma unroll 13
    for (int zs = 0; zs < NZS; zs++) {
        const float4 v = *reinterpret_cast<const float4*>(
            voxS + ((((size_t)b*NZS + zs)*(YW*VR) + rw)<<4) + q*4);
        a0 += rintf(v.x); a1 += rintf(v.y); a2 += rintf(v.z); a3 += rintf(v.w);
    }
    *reinterpret_cast<float4*>(dst) = make_float4(
        clamp01(a0/5.0f), clamp01(a1/5.0f), clamp01(a2/5.0f), clamp01(a3/5.0f));
}

// ---------------- fused rotate+translate + max, thread per (b,Y,X), all channels ----------------
// Geometry (<=16 combined taps of proj) computed ONCE per pixel, then a channel
// loop does 5 float4 loads per tap. Combined weight = w_trans * w_rot (exact
// composition up to f32 reassociation; output tolerance dwarfs it).
__global__ void rottrans_k(const float* __restrict__ proj, const float* __restrict__ aux,
                           const float* __restrict__ maps, float* __restrict__ out1) {
    int t = blockIdx.x*blockDim.x + threadIdx.x;
    if (t >= NB*MD*MD) return;
    int X = t % MD; int rest = t / MD;
    int Y = rest % MD; int b = rest / MD;
    float ct = aux[b*4+0], st = aux[b*4+1];
    float tx = aux[b*4+2], ty = aux[b*4+3];
    const float step = 2.0f/239.0f;
    float Xg = (X == MD-1) ? 1.0f : (-1.0f + (float)X*step);
    float Yg = (Y == MD-1) ? 1.0f : (-1.0f + (float)Y*step);
    float x = (Xg + tx + 1.0f)*119.5f;
    float y = (Yg + ty + 1.0f)*119.5f;
    float x0 = floorf(x), y0 = floorf(y);

    // 16 static tap slots: offset into proj pixel index, combined weight (0 if dead)
    int   toff[16];
    float twgt[16];
    #pragma unroll
    for (int tt = 0; tt < 4; tt++) {
        float ix = x0 + (float)(tt & 1);
        float iy = y0 + (float)(tt >> 1);
        float wt = ((tt & 1) ? (x - x0) : (x0 + 1.0f - x)) *
                   ((tt >> 1) ? (y - y0) : (y0 + 1.0f - y));
        bool tvalid = (ix >= 0.0f) && (ix < 240.0f) && (iy >= 0.0f) && (iy < 240.0f) && (wt != 0.0f);
        float u = 0.0f, v = 0.0f;
        if (tvalid) {
            int Xi = (int)ix, Yi = (int)iy;
            float Xg2 = (Xi == MD-1) ? 1.0f : (-1.0f + (float)Xi*step);
            float Yg2 = (Yi == MD-1) ? 1.0f : (-1.0f + (float)Yi*step);
            u = ct*Xg2 - st*Yg2;
            v = st*Xg2 + ct*Yg2;
        }
        float x2 = (u + 1.0f)*119.5f;
        float y2 = (v + 1.0f)*119.5f;
        float x20 = floorf(x2), y20 = floorf(y2);
        #pragma unroll
        for (int ii = 0; ii < 4; ii++) {
            float jx = x20 + (float)(ii & 1);
            float jy = y20 + (float)(ii >> 1);
            float w2 = ((ii & 1) ? (x2 - x20) : (x20 + 1.0f - x2)) *
                       ((ii >> 1) ? (y2 - y20) : (y20 + 1.0f - y2));
            bool ivalid = tvalid && (jy >= 120.0f) && (jy < 220.0f) && (jx >= 70.0f) && (jx < 170.0f);
            int slot = tt*4 + ii;
            twgt[slot] = ivalid ? wt * w2 : 0.0f;
            toff[slot] = ivalid ? (((int)jy - 120)*VR + ((int)jx - 70)) : 0;
        }
    }

    const float* pj = proj + (size_t)b*(VR*VR)*PC;
    float acc[PC];
    #pragma unroll
    for (int c = 0; c < PC; c++) acc[c] = 0.0f;
    #pragma unroll
    for (int s = 0; s < 16; s++) {
        float w = twgt[s];
        if (w == 0.0f) continue;
        const float* tp = pj + (size_t)toff[s]*PC;
        #pragma unroll
        for (int q = 0; q < 5; q++) {
            float4 v4 = *reinterpret_cast<const float4*>(tp + q*4);
            acc[q*4+0] += w*v4.x; acc[q*4+1] += w*v4.y;
            acc[q*4+2] += w*v4.z; acc[q*4+3] += w*v4.w;
        }
    }

    size_t obase = ((size_t)b*NCH)*(MD*MD) + (size_t)Y*MD + X;
    #pragma unroll
    for (int ch = 0; ch < NCH; ch++) {
        float m = maps[obase + (size_t)ch*(MD*MD)];
        float val = (ch == 2 || ch == 3) ? 0.0f : acc[ch];
        out1[obase + (size_t)ch*(MD*MD)] = fmaxf(m, val);
    }
}

extern "C" void kernel_launch(void* const* d_in, const int* in_sizes, int n_in,
                              void* d_out, int out_size, void* d_ws, size_t ws_size,
                              hipStream_t stream) {
    const float* obs        = (const float*)d_in[0];
    const float* pose_obs   = (const float*)d_in[1];
    const float* maps_last  = (const float*)d_in[2];
    const float* poses_last = (const float*)d_in[3];
    float* out  = (float*)d_out;
    float* out0 = out;                        // fp_map_pred: 8*1*100*100
    float* out1 = out + 80000;                // map_pred: 8*20*240*240
    float* out2 = out + 80000 + 9216000;      // poses
    float* out3 = out2 + 24;                  // poses (again)

    float* ws   = (float*)d_ws;
    float* vox0 = ws;                         // 8*80*64*100          = 4,096,000
    float* voxS = ws + 4096000;               // 8*26*64*100*16       = 21,299,200
    float* proj = ws + 4096000 + 21299200;    // 8*100*100*20         = 1,600,000
    float* aux  = ws + 4096000 + 21299200 + 1600000;  // 8*4

    const float FLf = (float)(80.0 / tan(39.5 * M_PI / 180.0));

    // zero only the voxel accumulators (everything else is fully overwritten)
    hipMemsetAsync(vox0, 0, (size_t)(4096000 + 21299200)*sizeof(float), stream);
    pose_k     <<<1, 64, 0, stream>>>(pose_obs, poses_last, out2, out3, aux);
    splat0_k   <<<(NB*HW*8 + 255)/256, 256, 0, stream>>>(obs, vox0, FLf);
    splatS_k   <<<(NB*HW*NSEM + 255)/256, 256, 0, stream>>>(obs, voxS, FLf);
    proj_main_k<<<(NB*VR*VR + 255)/256, 256, 0, stream>>>(vox0, proj, out0);
    proj_sem_k <<<(NB*VR*VR*4 + 255)/256, 256, 0, stream>>>(voxS, proj);
    rottrans_k <<<(NB*MD*MD + 255)/256, 256, 0, stream>>>(proj, aux, maps_last, out1);
}

// Round 5
// 147.089 us; speedup vs baseline: 4.7188x; 1.0082x over previous
//
#include <hip/hip_runtime.h>
#include <math.h>

#define NB 8
#define NH 120
#define NW 160
#define HW (NH*NW)
#define NSEM 16
#define NCH 20
#define VR 100
#define NZ 80
#define ZLO 9
#define ZHI 35
#define NZS (ZHI-ZLO)
#define MD 240
#define PC 20   // proj channel stride (channel-innermost, slot == output channel, 2/3 unused)
#define YW 64   // y-window rows actually touchable by the splat (posy = d/5 in [10,70])
#define YOFF 8
#define QSCALE 1024.0f
#define QINV   0.0009765625f

__device__ __forceinline__ float clamp01(float v){ return fminf(fmaxf(v, 0.0f), 1.0f); }

// Shared coordinate/weight computation (exact replica of reference f32 math).
struct SplatCoord {
    float wx[2], wy[2], wz[2];
    int xi[2], yi[2], zi[2];
};
__device__ __forceinline__ void compute_coord(float d, int h, int w, float fl, SplatCoord& sc) {
    float X = ((float)w - 79.5f) * d / fl;
    float Z = ((float)(119 - h) - 59.5f) * d / fl;
    float pcx = X + 250.0f;
    float pcy = d;
    float pcz = Z + 88.0f;
    float posx = ((pcx/5.0f - 50.0f)/100.0f*2.0f)*50.0f + 50.0f;
    float posy = ((pcy/5.0f - 50.0f)/100.0f*2.0f)*50.0f + 50.0f;
    float posz = ((pcz/5.0f - 32.0f)/80.0f*2.0f)*40.0f + 40.0f;
    float f;
    f = floorf(posx);
    #pragma unroll
    for (int i = 0; i < 2; i++) {
        float pi = f + (float)i; bool s = (pi > 0.0f) && (pi < 100.0f);
        sc.wx[i] = s ? (1.0f - fabsf(posx - pi)) : 0.0f; sc.xi[i] = s ? (int)pi : 0;
    }
    f = floorf(posy);
    #pragma unroll
    for (int i = 0; i < 2; i++) {
        float pi = f + (float)i; bool s = (pi > 0.0f) && (pi < 100.0f);
        sc.wy[i] = s ? (1.0f - fabsf(posy - pi)) : 0.0f; sc.yi[i] = s ? (int)pi : 0;
    }
    f = floorf(posz);
    #pragma unroll
    for (int i = 0; i < 2; i++) {
        float pi = f + (float)i; bool s = (pi > 0.0f) && (pi < 80.0f);
        sc.wz[i] = s ? (1.0f - fabsf(posz - pi)) : 0.0f; sc.zi[i] = s ? (int)pi : 0;
    }
}

// ---------------- pose + affine params ----------------
__global__ void pose_k(const float* __restrict__ pose_obs,
                       const float* __restrict__ poses_last,
                       float* __restrict__ out2, float* __restrict__ out3,
                       float* __restrict__ aux) {
    int b = threadIdx.x;
    if (b >= NB) return;
    const float D2R = 0.017453292519943295f;
    float th = poses_last[b*3+2] * D2R;
    float s = sinf(th), c = cosf(th);
    float ny = poses_last[b*3+1] + pose_obs[b*3+0]*s + pose_obs[b*3+1]*c;
    float nx = poses_last[b*3+0] + pose_obs[b*3+0]*c - pose_obs[b*3+1]*s;
    float nt = poses_last[b*3+2] + pose_obs[b*3+2]*57.29577951308232f;
    nt = fmodf(nt - 180.0f, 360.0f) + 180.0f;
    nt = fmodf(nt + 180.0f, 360.0f) - 180.0f;
    out2[b*3+0] = nx; out2[b*3+1] = ny; out2[b*3+2] = nt;
    out3[b*3+0] = nx; out3[b*3+1] = ny; out3[b*3+2] = nt;
    float stt = 90.0f - nt;
    float rad = stt * D2R;
    aux[b*4+0] = cosf(rad);
    aux[b*4+1] = sinf(rad);
    aux[b*4+2] = -(nx*100.0f/5.0f - 120.0f)/120.0f;  // st_xy[:,0]
    aux[b*4+3] = -(ny*100.0f/5.0f - 120.0f)/120.0f;  // st_xy[:,1]
}

// ---------------- fused splat ----------------
// region A (t < NB*HW*8): ch0, thread per (pixel, corner) -> f32 atomic into vox0[b][z][yw][x]
// region B: sem, thread per (pixel, channel-pair) -> u32 packed (2x16b, scale 1024)
//           atomic into voxS[b][zs][yw][x][cp8]
__global__ void splat_k(const float* __restrict__ obs, float* __restrict__ vox0,
                        unsigned* __restrict__ voxS, float fl) {
    int t = blockIdx.x*blockDim.x + threadIdx.x;
    bool sem = (t >= NB*HW*8);
    int tt = sem ? t - NB*HW*8 : t;
    if (tt >= NB*HW*8) return;
    int k = tt & 7; int pp = tt >> 3;
    int b = pp / HW, p = pp % HW;
    int h = p / NW, w = p % NW;
    const float* ob = obs + (size_t)b*NCH*HW;
    float d = ob[3*HW + p];
    SplatCoord sc;
    compute_coord(d, h, w, fl, sc);
    if (!sem) {
        int cx = k & 1, cy = (k >> 1) & 1, cz = k >> 2;
        float w3 = (sc.wx[cx]*sc.wy[cy])*sc.wz[cz];
        unsigned ywi = (unsigned)(sc.yi[cy] - YOFF);
        if (w3 != 0.0f && ywi < YW) {
            atomicAdd(&vox0[(((size_t)b*NZ + sc.zi[cz])*YW + ywi)*VR + sc.xi[cx]], w3);
        }
    } else {
        float f0 = ob[(4+2*k)*HW + p];
        float f1 = ob[(5+2*k)*HW + p];
        #pragma unroll
        for (int cz = 0; cz < 2; cz++) {
            int z = sc.zi[cz];
            if (z < ZLO || z >= ZHI) continue;
            float wzv = sc.wz[cz];
            #pragma unroll
            for (int cx = 0; cx < 2; cx++)
            #pragma unroll
            for (int cy = 0; cy < 2; cy++) {
                float w3 = (sc.wx[cx]*sc.wy[cy])*wzv;
                unsigned ywi = (unsigned)(sc.yi[cy] - YOFF);
                if (w3 == 0.0f || ywi >= YW) continue;
                unsigned q0 = __float2uint_rn(f0*w3*QSCALE);
                unsigned q1 = __float2uint_rn(f1*w3*QSCALE);
                unsigned val = q0 | (q1 << 16);
                if (val) {
                    size_t addr = (((((size_t)b*NZS + (z-ZLO))*YW + ywi)*VR + sc.xi[cx])<<3) + k;
                    atomicAdd(&voxS[addr], val);
                }
            }
        }
    }
}

// ---------------- fused projections ----------------
// region A (t < NB*VR*VR): ch0 -> proj slots 0,1 + out0
// region B: sem halves, thread per (b,pixel,half): decode 8 packed channels -> proj slots 4+8h..
__global__ void proj_k(const float* __restrict__ vox0, const unsigned* __restrict__ voxS,
                       float* __restrict__ proj, float* __restrict__ out0) {
    int t = blockIdx.x*blockDim.x + threadIdx.x;
    if (t < NB*VR*VR) {
        int b = t / (VR*VR), r = t % (VR*VR);
        int yy = r / VR;
        float* pb = proj + ((size_t)b*(VR*VR) + r)*PC;
        if (yy < YOFF || yy >= YOFF+YW) {
            out0[(size_t)b*(VR*VR) + r] = 0.0f;
            *reinterpret_cast<float2*>(pb) = make_float2(0.0f, 0.0f);
            return;
        }
        int rw = (yy - YOFF)*VR + (r % VR);
        float s_all = 0.0f, s_slab = 0.0f;
        #pragma unroll 16
        for (int z = 0; z < NZ; z++) {
            float v = rintf(vox0[((size_t)b*NZ + z)*(YW*VR) + rw]);
            s_all += v;
            if (z >= ZLO && z < ZHI) s_slab += v;
        }
        float fpm = clamp01(s_slab);  // MAP_THR = 1
        float fpe = clamp01(s_all);   // EXP_THR = 1
        out0[(size_t)b*(VR*VR) + r] = fpm;
        *reinterpret_cast<float2*>(pb) = make_float2(fpm, fpe);
        return;
    }
    int t2 = t - NB*VR*VR;
    if (t2 >= NB*VR*VR*2) return;
    int hf = t2 & 1; int rr = t2 >> 1;
    int b = rr / (VR*VR), r = rr % (VR*VR);
    int yy = r / VR;
    float* dst = proj + ((size_t)b*(VR*VR) + r)*PC + 4 + hf*8;  // 16B aligned
    if (yy < YOFF || yy >= YOFF+YW) {
        *reinterpret_cast<float4*>(dst)     = make_float4(0.0f, 0.0f, 0.0f, 0.0f);
        *reinterpret_cast<float4*>(dst + 4) = make_float4(0.0f, 0.0f, 0.0f, 0.0f);
        return;
    }
    int rw = (yy - YOFF)*VR + (r % VR);
    float a[8];
    #pragma unroll
    for (int i = 0; i < 8; i++) a[i] = 0.0f;
    #pragma unroll 13
    for (int zs = 0; zs < NZS; zs++) {
        const uint4 v = *reinterpret_cast<const uint4*>(
            voxS + ((((size_t)b*NZS + zs)*(YW*VR) + rw)<<3) + hf*4);
        a[0] += rintf((float)(v.x & 0xFFFFu)*QINV); a[1] += rintf((float)(v.x >> 16)*QINV);
        a[2] += rintf((float)(v.y & 0xFFFFu)*QINV); a[3] += rintf((float)(v.y >> 16)*QINV);
        a[4] += rintf((float)(v.z & 0xFFFFu)*QINV); a[5] += rintf((float)(v.z >> 16)*QINV);
        a[6] += rintf((float)(v.w & 0xFFFFu)*QINV); a[7] += rintf((float)(v.w >> 16)*QINV);
    }
    *reinterpret_cast<float4*>(dst) = make_float4(
        clamp01(a[0]/5.0f), clamp01(a[1]/5.0f), clamp01(a[2]/5.0f), clamp01(a[3]/5.0f));
    *reinterpret_cast<float4*>(dst + 4) = make_float4(
        clamp01(a[4]/5.0f), clamp01(a[5]/5.0f), clamp01(a[6]/5.0f), clamp01(a[7]/5.0f));
}

// ---------------- fused rotate+translate + max, thread per (b,Y,X), all channels ----------------
__global__ void rottrans_k(const float* __restrict__ proj, const float* __restrict__ aux,
                           const float* __restrict__ maps, float* __restrict__ out1) {
    int t = blockIdx.x*blockDim.x + threadIdx.x;
    if (t >= NB*MD*MD) return;
    int X = t % MD; int rest = t / MD;
    int Y = rest % MD; int b = rest / MD;
    float ct = aux[b*4+0], st = aux[b*4+1];
    float tx = aux[b*4+2], ty = aux[b*4+3];
    const float step = 2.0f/239.0f;
    float Xg = (X == MD-1) ? 1.0f : (-1.0f + (float)X*step);
    float Yg = (Y == MD-1) ? 1.0f : (-1.0f + (float)Y*step);
    float x = (Xg + tx + 1.0f)*119.5f;
    float y = (Yg + ty + 1.0f)*119.5f;
    float x0 = floorf(x), y0 = floorf(y);

    int   toff[16];
    float twgt[16];
    #pragma unroll
    for (int tt = 0; tt < 4; tt++) {
        float ix = x0 + (float)(tt & 1);
        float iy = y0 + (float)(tt >> 1);
        float wt = ((tt & 1) ? (x - x0) : (x0 + 1.0f - x)) *
                   ((tt >> 1) ? (y - y0) : (y0 + 1.0f - y));
        bool tvalid = (ix >= 0.0f) && (ix < 240.0f) && (iy >= 0.0f) && (iy < 240.0f) && (wt != 0.0f);
        float u = 0.0f, v = 0.0f;
        if (tvalid) {
            int Xi = (int)ix, Yi = (int)iy;
            float Xg2 = (Xi == MD-1) ? 1.0f : (-1.0f + (float)Xi*step);
            float Yg2 = (Yi == MD-1) ? 1.0f : (-1.0f + (float)Yi*step);
            u = ct*Xg2 - st*Yg2;
            v = st*Xg2 + ct*Yg2;
        }
        float x2 = (u + 1.0f)*119.5f;
        float y2 = (v + 1.0f)*119.5f;
        float x20 = floorf(x2), y20 = floorf(y2);
        #pragma unroll
        for (int ii = 0; ii < 4; ii++) {
            float jx = x20 + (float)(ii & 1);
            float jy = y20 + (float)(ii >> 1);
            float w2 = ((ii & 1) ? (x2 - x20) : (x20 + 1.0f - x2)) *
                       ((ii >> 1) ? (y2 - y20) : (y20 + 1.0f - y2));
            bool ivalid = tvalid && (jy >= 120.0f) && (jy < 220.0f) && (jx >= 70.0f) && (jx < 170.0f);
            int slot = tt*4 + ii;
            twgt[slot] = ivalid ? wt * w2 : 0.0f;
            toff[slot] = ivalid ? (((int)jy - 120)*VR + ((int)jx - 70)) : 0;
        }
    }

    const float* pj = proj + (size_t)b*(VR*VR)*PC;
    float acc[PC];
    #pragma unroll
    for (int c = 0; c < PC; c++) acc[c] = 0.0f;
    #pragma unroll
    for (int s = 0; s < 16; s++) {
        float w = twgt[s];
        if (w == 0.0f) continue;
        const float* tp = pj + (size_t)toff[s]*PC;
        #pragma unroll
        for (int q = 0; q < 5; q++) {
            float4 v4 = *reinterpret_cast<const float4*>(tp + q*4);
            acc[q*4+0] += w*v4.x; acc[q*4+1] += w*v4.y;
            acc[q*4+2] += w*v4.z; acc[q*4+3] += w*v4.w;
        }
    }

    size_t obase = ((size_t)b*NCH)*(MD*MD) + (size_t)Y*MD + X;
    #pragma unroll
    for (int ch = 0; ch < NCH; ch++) {
        float m = maps[obase + (size_t)ch*(MD*MD)];
        float val = (ch == 2 || ch == 3) ? 0.0f : acc[ch];
        out1[obase + (size_t)ch*(MD*MD)] = fmaxf(m, val);
    }
}

extern "C" void kernel_launch(void* const* d_in, const int* in_sizes, int n_in,
                              void* d_out, int out_size, void* d_ws, size_t ws_size,
                              hipStream_t stream) {
    const float* obs        = (const float*)d_in[0];
    const float* pose_obs   = (const float*)d_in[1];
    const float* maps_last  = (const float*)d_in[2];
    const float* poses_last = (const float*)d_in[3];
    float* out  = (float*)d_out;
    float* out0 = out;                        // fp_map_pred: 8*1*100*100
    float* out1 = out + 80000;                // map_pred: 8*20*240*240
    float* out2 = out + 80000 + 9216000;      // poses
    float* out3 = out2 + 24;                  // poses (again)

    float*    ws   = (float*)d_ws;
    float*    vox0 = ws;                               // 8*80*64*100 f32        = 4,096,000
    unsigned* voxS = (unsigned*)(ws + 4096000);        // 8*26*64*100*8 u32      = 10,649,600
    float*    proj = ws + 4096000 + 10649600;          // 8*100*100*20 f32       = 1,600,000
    float*    aux  = ws + 4096000 + 10649600 + 1600000;  // 8*4

    const float FLf = (float)(80.0 / tan(39.5 * M_PI / 180.0));

    // zero the voxel accumulators (vox0 f32 + voxS u32, contiguous)
    hipMemsetAsync(vox0, 0, (size_t)(4096000 + 10649600)*sizeof(float), stream);
    pose_k    <<<1, 64, 0, stream>>>(pose_obs, poses_last, out2, out3, aux);
    splat_k   <<<(2*NB*HW*8 + 255)/256, 256, 0, stream>>>(obs, vox0, voxS, FLf);
    proj_k    <<<(3*NB*VR*VR + 255)/256, 256, 0, stream>>>(vox0, voxS, proj, out0);
    rottrans_k<<<(NB*MD*MD + 255)/256, 256, 0, stream>>>(proj, aux, maps_last, out1);
}

// Round 6
// 146.971 us; speedup vs baseline: 4.7225x; 1.0008x over previous
//
#include <hip/hip_runtime.h>
#include <math.h>

#define NB 8
#define NH 120
#define NW 160
#define HW (NH*NW)
#define NSEM 16
#define NCH 20
#define VR 100
#define NZ 80
#define ZLO 9
#define ZHI 35
#define NZS (ZHI-ZLO)
#define MD 240
#define PC 20   // proj channel stride (channel-innermost, slot == output channel, 2/3 unused)
#define YW 64   // y-window rows actually touchable by the splat (posy = d/5 in [10,70])
#define YOFF 8
#define QSCALE 1024.0f
#define QINV   0.0009765625f

__device__ __forceinline__ float clamp01(float v){ return fminf(fmaxf(v, 0.0f), 1.0f); }

// Raw VMEM atomics via inline asm: guarantees global_atomic_* instructions with
// no compiler atomic-lowering (round 5's atomicAdd was transformed into a 48KB
// LDS aggregation path -> occupancy 27%, 3.4M bank conflicts).
__device__ __forceinline__ void atom_add_u32(unsigned* p, unsigned v) {
    asm volatile("global_atomic_add %0, %1, off" :: "v"(p), "v"(v) : "memory");
}
__device__ __forceinline__ void atom_add_f32(float* p, float v) {
    asm volatile("global_atomic_add_f32 %0, %1, off" :: "v"(p), "v"(v) : "memory");
}

// Shared coordinate/weight computation (exact replica of reference f32 math).
struct SplatCoord {
    float wx[2], wy[2], wz[2];
    int xi[2], yi[2], zi[2];
};
__device__ __forceinline__ void compute_coord(float d, int h, int w, float fl, SplatCoord& sc) {
    float X = ((float)w - 79.5f) * d / fl;
    float Z = ((float)(119 - h) - 59.5f) * d / fl;
    float pcx = X + 250.0f;
    float pcy = d;
    float pcz = Z + 88.0f;
    float posx = ((pcx/5.0f - 50.0f)/100.0f*2.0f)*50.0f + 50.0f;
    float posy = ((pcy/5.0f - 50.0f)/100.0f*2.0f)*50.0f + 50.0f;
    float posz = ((pcz/5.0f - 32.0f)/80.0f*2.0f)*40.0f + 40.0f;
    float f;
    f = floorf(posx);
    #pragma unroll
    for (int i = 0; i < 2; i++) {
        float pi = f + (float)i; bool s = (pi > 0.0f) && (pi < 100.0f);
        sc.wx[i] = s ? (1.0f - fabsf(posx - pi)) : 0.0f; sc.xi[i] = s ? (int)pi : 0;
    }
    f = floorf(posy);
    #pragma unroll
    for (int i = 0; i < 2; i++) {
        float pi = f + (float)i; bool s = (pi > 0.0f) && (pi < 100.0f);
        sc.wy[i] = s ? (1.0f - fabsf(posy - pi)) : 0.0f; sc.yi[i] = s ? (int)pi : 0;
    }
    f = floorf(posz);
    #pragma unroll
    for (int i = 0; i < 2; i++) {
        float pi = f + (float)i; bool s = (pi > 0.0f) && (pi < 80.0f);
        sc.wz[i] = s ? (1.0f - fabsf(posz - pi)) : 0.0f; sc.zi[i] = s ? (int)pi : 0;
    }
}

// ---------------- pose + affine params ----------------
__global__ void pose_k(const float* __restrict__ pose_obs,
                       const float* __restrict__ poses_last,
                       float* __restrict__ out2, float* __restrict__ out3,
                       float* __restrict__ aux) {
    int b = threadIdx.x;
    if (b >= NB) return;
    const float D2R = 0.017453292519943295f;
    float th = poses_last[b*3+2] * D2R;
    float s = sinf(th), c = cosf(th);
    float ny = poses_last[b*3+1] + pose_obs[b*3+0]*s + pose_obs[b*3+1]*c;
    float nx = poses_last[b*3+0] + pose_obs[b*3+0]*c - pose_obs[b*3+1]*s;
    float nt = poses_last[b*3+2] + pose_obs[b*3+2]*57.29577951308232f;
    nt = fmodf(nt - 180.0f, 360.0f) + 180.0f;
    nt = fmodf(nt + 180.0f, 360.0f) - 180.0f;
    out2[b*3+0] = nx; out2[b*3+1] = ny; out2[b*3+2] = nt;
    out3[b*3+0] = nx; out3[b*3+1] = ny; out3[b*3+2] = nt;
    float stt = 90.0f - nt;
    float rad = stt * D2R;
    aux[b*4+0] = cosf(rad);
    aux[b*4+1] = sinf(rad);
    aux[b*4+2] = -(nx*100.0f/5.0f - 120.0f)/120.0f;  // st_xy[:,0]
    aux[b*4+3] = -(ny*100.0f/5.0f - 120.0f)/120.0f;  // st_xy[:,1]
}

// ---------------- fused splat ----------------
// region A (t < NB*HW*8): ch0, thread per (pixel, corner) -> f32 atomic into vox0[b][z][yw][x]
// region B: sem, thread per (pixel, channel-pair) -> u32 packed (2x16b, scale 1024)
//           atomic into voxS[b][zs][yw][x][cp8]
__global__ void splat_k(const float* __restrict__ obs, float* __restrict__ vox0,
                        unsigned* __restrict__ voxS, float fl) {
    int t = blockIdx.x*blockDim.x + threadIdx.x;
    bool sem = (t >= NB*HW*8);
    int tt = sem ? t - NB*HW*8 : t;
    if (tt >= NB*HW*8) return;
    int k = tt & 7; int pp = tt >> 3;
    int b = pp / HW, p = pp % HW;
    int h = p / NW, w = p % NW;
    const float* ob = obs + (size_t)b*NCH*HW;
    float d = ob[3*HW + p];
    SplatCoord sc;
    compute_coord(d, h, w, fl, sc);
    if (!sem) {
        int cx = k & 1, cy = (k >> 1) & 1, cz = k >> 2;
        float w3 = (sc.wx[cx]*sc.wy[cy])*sc.wz[cz];
        unsigned ywi = (unsigned)(sc.yi[cy] - YOFF);
        if (w3 != 0.0f && ywi < YW) {
            atom_add_f32(&vox0[(((size_t)b*NZ + sc.zi[cz])*YW + ywi)*VR + sc.xi[cx]], w3);
        }
    } else {
        float f0 = ob[(4+2*k)*HW + p];
        float f1 = ob[(5+2*k)*HW + p];
        #pragma unroll
        for (int cz = 0; cz < 2; cz++) {
            int z = sc.zi[cz];
            if (z < ZLO || z >= ZHI) continue;
            float wzv = sc.wz[cz];
            #pragma unroll
            for (int cx = 0; cx < 2; cx++)
            #pragma unroll
            for (int cy = 0; cy < 2; cy++) {
                float w3 = (sc.wx[cx]*sc.wy[cy])*wzv;
                unsigned ywi = (unsigned)(sc.yi[cy] - YOFF);
                if (w3 == 0.0f || ywi >= YW) continue;
                unsigned q0 = __float2uint_rn(f0*w3*QSCALE);
                unsigned q1 = __float2uint_rn(f1*w3*QSCALE);
                unsigned val = q0 | (q1 << 16);
                if (val) {
                    size_t addr = (((((size_t)b*NZS + (z-ZLO))*YW + ywi)*VR + sc.xi[cx])<<3) + k;
                    atom_add_u32(&voxS[addr], val);
                }
            }
        }
    }
}

// ---------------- fused projections ----------------
// region A (t < NB*VR*VR): ch0 -> proj slots 0,1 + out0
// region B: sem halves, thread per (b,pixel,half): decode 8 packed channels -> proj slots 4+8h..
__global__ void proj_k(const float* __restrict__ vox0, const unsigned* __restrict__ voxS,
                       float* __restrict__ proj, float* __restrict__ out0) {
    int t = blockIdx.x*blockDim.x + threadIdx.x;
    if (t < NB*VR*VR) {
        int b = t / (VR*VR), r = t % (VR*VR);
        int yy = r / VR;
        float* pb = proj + ((size_t)b*(VR*VR) + r)*PC;
        if (yy < YOFF || yy >= YOFF+YW) {
            out0[(size_t)b*(VR*VR) + r] = 0.0f;
            *reinterpret_cast<float2*>(pb) = make_float2(0.0f, 0.0f);
            return;
        }
        int rw = (yy - YOFF)*VR + (r % VR);
        float s_all = 0.0f, s_slab = 0.0f;
        #pragma unroll 16
        for (int z = 0; z < NZ; z++) {
            float v = rintf(vox0[((size_t)b*NZ + z)*(YW*VR) + rw]);
            s_all += v;
            if (z >= ZLO && z < ZHI) s_slab += v;
        }
        float fpm = clamp01(s_slab);  // MAP_THR = 1
        float fpe = clamp01(s_all);   // EXP_THR = 1
        out0[(size_t)b*(VR*VR) + r] = fpm;
        *reinterpret_cast<float2*>(pb) = make_float2(fpm, fpe);
        return;
    }
    int t2 = t - NB*VR*VR;
    if (t2 >= NB*VR*VR*2) return;
    int hf = t2 & 1; int rr = t2 >> 1;
    int b = rr / (VR*VR), r = rr % (VR*VR);
    int yy = r / VR;
    float* dst = proj + ((size_t)b*(VR*VR) + r)*PC + 4 + hf*8;  // 16B aligned
    if (yy < YOFF || yy >= YOFF+YW) {
        *reinterpret_cast<float4*>(dst)     = make_float4(0.0f, 0.0f, 0.0f, 0.0f);
        *reinterpret_cast<float4*>(dst + 4) = make_float4(0.0f, 0.0f, 0.0f, 0.0f);
        return;
    }
    int rw = (yy - YOFF)*VR + (r % VR);
    float a[8];
    #pragma unroll
    for (int i = 0; i < 8; i++) a[i] = 0.0f;
    #pragma unroll 13
    for (int zs = 0; zs < NZS; zs++) {
        const uint4 v = *reinterpret_cast<const uint4*>(
            voxS + ((((size_t)b*NZS + zs)*(YW*VR) + rw)<<3) + hf*4);
        a[0] += rintf((float)(v.x & 0xFFFFu)*QINV); a[1] += rintf((float)(v.x >> 16)*QINV);
        a[2] += rintf((float)(v.y & 0xFFFFu)*QINV); a[3] += rintf((float)(v.y >> 16)*QINV);
        a[4] += rintf((float)(v.z & 0xFFFFu)*QINV); a[5] += rintf((float)(v.z >> 16)*QINV);
        a[6] += rintf((float)(v.w & 0xFFFFu)*QINV); a[7] += rintf((float)(v.w >> 16)*QINV);
    }
    *reinterpret_cast<float4*>(dst) = make_float4(
        clamp01(a[0]/5.0f), clamp01(a[1]/5.0f), clamp01(a[2]/5.0f), clamp01(a[3]/5.0f));
    *reinterpret_cast<float4*>(dst + 4) = make_float4(
        clamp01(a[4]/5.0f), clamp01(a[5]/5.0f), clamp01(a[6]/5.0f), clamp01(a[7]/5.0f));
}

// ---------------- fused rotate+translate + max, thread per (b,Y,X), all channels ----------------
__global__ void rottrans_k(const float* __restrict__ proj, const float* __restrict__ aux,
                           const float* __restrict__ maps, float* __restrict__ out1) {
    int t = blockIdx.x*blockDim.x + threadIdx.x;
    if (t >= NB*MD*MD) return;
    int X = t % MD; int rest = t / MD;
    int Y = rest % MD; int b = rest / MD;
    float ct = aux[b*4+0], st = aux[b*4+1];
    float tx = aux[b*4+2], ty = aux[b*4+3];
    const float step = 2.0f/239.0f;
    float Xg = (X == MD-1) ? 1.0f : (-1.0f + (float)X*step);
    float Yg = (Y == MD-1) ? 1.0f : (-1.0f + (float)Y*step);
    float x = (Xg + tx + 1.0f)*119.5f;
    float y = (Yg + ty + 1.0f)*119.5f;
    float x0 = floorf(x), y0 = floorf(y);

    int   toff[16];
    float twgt[16];
    #pragma unroll
    for (int tt = 0; tt < 4; tt++) {
        float ix = x0 + (float)(tt & 1);
        float iy = y0 + (float)(tt >> 1);
        float wt = ((tt & 1) ? (x - x0) : (x0 + 1.0f - x)) *
                   ((tt >> 1) ? (y - y0) : (y0 + 1.0f - y));
        bool tvalid = (ix >= 0.0f) && (ix < 240.0f) && (iy >= 0.0f) && (iy < 240.0f) && (wt != 0.0f);
        float u = 0.0f, v = 0.0f;
        if (tvalid) {
            int Xi = (int)ix, Yi = (int)iy;
            float Xg2 = (Xi == MD-1) ? 1.0f : (-1.0f + (float)Xi*step);
            float Yg2 = (Yi == MD-1) ? 1.0f : (-1.0f + (float)Yi*step);
            u = ct*Xg2 - st*Yg2;
            v = st*Xg2 + ct*Yg2;
        }
        float x2 = (u + 1.0f)*119.5f;
        float y2 = (v + 1.0f)*119.5f;
        float x20 = floorf(x2), y20 = floorf(y2);
        #pragma unroll
        for (int ii = 0; ii < 4; ii++) {
            float jx = x20 + (float)(ii & 1);
            float jy = y20 + (float)(ii >> 1);
            float w2 = ((ii & 1) ? (x2 - x20) : (x20 + 1.0f - x2)) *
                       ((ii >> 1) ? (y2 - y20) : (y20 + 1.0f - y2));
            bool ivalid = tvalid && (jy >= 120.0f) && (jy < 220.0f) && (jx >= 70.0f) && (jx < 170.0f);
            int slot = tt*4 + ii;
            twgt[slot] = ivalid ? wt * w2 : 0.0f;
            toff[slot] = ivalid ? (((int)jy - 120)*VR + ((int)jx - 70)) : 0;
        }
    }

    const float* pj = proj + (size_t)b*(VR*VR)*PC;
    float acc[PC];
    #pragma unroll
    for (int c = 0; c < PC; c++) acc[c] = 0.0f;
    #pragma unroll
    for (int s = 0; s < 16; s++) {
        float w = twgt[s];
        if (w == 0.0f) continue;
        const float* tp = pj + (size_t)toff[s]*PC;
        #pragma unroll
        for (int q = 0; q < 5; q++) {
            float4 v4 = *reinterpret_cast<const float4*>(tp + q*4);
            acc[q*4+0] += w*v4.x; acc[q*4+1] += w*v4.y;
            acc[q*4+2] += w*v4.z; acc[q*4+3] += w*v4.w;
        }
    }

    size_t obase = ((size_t)b*NCH)*(MD*MD) + (size_t)Y*MD + X;
    #pragma unroll
    for (int ch = 0; ch < NCH; ch++) {
        float m = maps[obase + (size_t)ch*(MD*MD)];
        float val = (ch == 2 || ch == 3) ? 0.0f : acc[ch];
        out1[obase + (size_t)ch*(MD*MD)] = fmaxf(m, val);
    }
}

extern "C" void kernel_launch(void* const* d_in, const int* in_sizes, int n_in,
                              void* d_out, int out_size, void* d_ws, size_t ws_size,
                              hipStream_t stream) {
    const float* obs        = (const float*)d_in[0];
    const float* pose_obs   = (const float*)d_in[1];
    const float* maps_last  = (const float*)d_in[2];
    const float* poses_last = (const float*)d_in[3];
    float* out  = (float*)d_out;
    float* out0 = out;                        // fp_map_pred: 8*1*100*100
    float* out1 = out + 80000;                // map_pred: 8*20*240*240
    float* out2 = out + 80000 + 9216000;      // poses
    float* out3 = out2 + 24;                  // poses (again)

    float*    ws   = (float*)d_ws;
    float*    vox0 = ws;                               // 8*80*64*100 f32        = 4,096,000
    unsigned* voxS = (unsigned*)(ws + 4096000);        // 8*26*64*100*8 u32      = 10,649,600
    float*    proj = ws + 4096000 + 10649600;          // 8*100*100*20 f32       = 1,600,000
    float*    aux  = ws + 4096000 + 10649600 + 1600000;  // 8*4

    const float FLf = (float)(80.0 / tan(39.5 * M_PI / 180.0));

    // zero the voxel accumulators (vox0 f32 + voxS u32, contiguous)
    hipMemsetAsync(vox0, 0, (size_t)(4096000 + 10649600)*sizeof(float), stream);
    pose_k    <<<1, 64, 0, stream>>>(pose_obs, poses_last, out2, out3, aux);
    splat_k   <<<(2*NB*HW*8 + 255)/256, 256, 0, stream>>>(obs, vox0, voxS, FLf);
    proj_k    <<<(3*NB*VR*VR + 255)/256, 256, 0, stream>>>(vox0, voxS, proj, out0);
    rottrans_k<<<(NB*MD*MD + 255)/256, 256, 0, stream>>>(proj, aux, maps_last, out1);
}

// Round 7
// 132.418 us; speedup vs baseline: 5.2416x; 1.1099x over previous
//
#include <hip/hip_runtime.h>
#include <math.h>

#define NB 8
#define NH 120
#define NW 160
#define HW (NH*NW)
#define NSEM 16
#define NCH 20
#define VR 100
#define NZ 80
#define ZLO 9
#define ZHI 35
#define NZS (ZHI-ZLO)
#define MD 240
#define PC 20   // proj channel stride (channel-innermost, slot == output channel, 2/3 unused)
#define YW 64   // y-window rows actually touchable by the splat (posy = d/5 in [10,70])
#define YOFF 8
#define QSCALE 1024.0f
#define QINV   0.0009765625f

__device__ __forceinline__ float clamp01(float v){ return fminf(fmaxf(v, 0.0f), 1.0f); }

// Scalar-field coordinate/weight computation (exact replica of reference f32 math).
// NO arrays: runtime-indexed arrays become allocas, which AMDGPUPromoteAlloca
// hoists into 48KB of LDS (rounds 5/6: occupancy 27%, 3.4M LDS bank conflicts).
struct SplatCoord {
    float wx0, wx1, wy0, wy1, wz0, wz1;
    int   xi0, xi1, yi0, yi1, zi0, zi1;
};
__device__ __forceinline__ void compute_coord(float d, int h, int w, float fl, SplatCoord& sc) {
    float X = ((float)w - 79.5f) * d / fl;
    float Z = ((float)(119 - h) - 59.5f) * d / fl;
    float pcx = X + 250.0f;
    float pcy = d;
    float pcz = Z + 88.0f;
    float posx = ((pcx/5.0f - 50.0f)/100.0f*2.0f)*50.0f + 50.0f;
    float posy = ((pcy/5.0f - 50.0f)/100.0f*2.0f)*50.0f + 50.0f;
    float posz = ((pcz/5.0f - 32.0f)/80.0f*2.0f)*40.0f + 40.0f;
    float f;
    f = floorf(posx);
    { float pi = f;        bool s = (pi > 0.0f) && (pi < 100.0f);
      sc.wx0 = s ? (1.0f - fabsf(posx - pi)) : 0.0f; sc.xi0 = s ? (int)pi : 0; }
    { float pi = f + 1.0f; bool s = (pi > 0.0f) && (pi < 100.0f);
      sc.wx1 = s ? (1.0f - fabsf(posx - pi)) : 0.0f; sc.xi1 = s ? (int)pi : 0; }
    f = floorf(posy);
    { float pi = f;        bool s = (pi > 0.0f) && (pi < 100.0f);
      sc.wy0 = s ? (1.0f - fabsf(posy - pi)) : 0.0f; sc.yi0 = s ? (int)pi : 0; }
    { float pi = f + 1.0f; bool s = (pi > 0.0f) && (pi < 100.0f);
      sc.wy1 = s ? (1.0f - fabsf(posy - pi)) : 0.0f; sc.yi1 = s ? (int)pi : 0; }
    f = floorf(posz);
    { float pi = f;        bool s = (pi > 0.0f) && (pi < 80.0f);
      sc.wz0 = s ? (1.0f - fabsf(posz - pi)) : 0.0f; sc.zi0 = s ? (int)pi : 0; }
    { float pi = f + 1.0f; bool s = (pi > 0.0f) && (pi < 80.0f);
      sc.wz1 = s ? (1.0f - fabsf(posz - pi)) : 0.0f; sc.zi1 = s ? (int)pi : 0; }
}

// ---------------- pose + affine params ----------------
__global__ void pose_k(const float* __restrict__ pose_obs,
                       const float* __restrict__ poses_last,
                       float* __restrict__ out2, float* __restrict__ out3,
                       float* __restrict__ aux) {
    int b = threadIdx.x;
    if (b >= NB) return;
    const float D2R = 0.017453292519943295f;
    float th = poses_last[b*3+2] * D2R;
    float s = sinf(th), c = cosf(th);
    float ny = poses_last[b*3+1] + pose_obs[b*3+0]*s + pose_obs[b*3+1]*c;
    float nx = poses_last[b*3+0] + pose_obs[b*3+0]*c - pose_obs[b*3+1]*s;
    float nt = poses_last[b*3+2] + pose_obs[b*3+2]*57.29577951308232f;
    nt = fmodf(nt - 180.0f, 360.0f) + 180.0f;
    nt = fmodf(nt + 180.0f, 360.0f) - 180.0f;
    out2[b*3+0] = nx; out2[b*3+1] = ny; out2[b*3+2] = nt;
    out3[b*3+0] = nx; out3[b*3+1] = ny; out3[b*3+2] = nt;
    float stt = 90.0f - nt;
    float rad = stt * D2R;
    aux[b*4+0] = cosf(rad);
    aux[b*4+1] = sinf(rad);
    aux[b*4+2] = -(nx*100.0f/5.0f - 120.0f)/120.0f;  // st_xy[:,0]
    aux[b*4+3] = -(ny*100.0f/5.0f - 120.0f)/120.0f;  // st_xy[:,1]
}

// ---------------- fused splat ----------------
// region A (t < NB*HW*8): ch0, thread per (pixel, corner) -> f32 atomic into vox0[b][z][yw][x]
// region B: sem, thread per (pixel, channel-pair) -> u32 packed (2x16b, scale 1024)
//           atomic into voxS[b][zs][yw][x][cp8]
__global__ void splat_k(const float* __restrict__ obs, float* __restrict__ vox0,
                        unsigned* __restrict__ voxS, float fl) {
    int t = blockIdx.x*blockDim.x + threadIdx.x;
    bool sem = (t >= NB*HW*8);
    int tt = sem ? t - NB*HW*8 : t;
    if (tt >= NB*HW*8) return;
    int k = tt & 7; int pp = tt >> 3;
    int b = pp / HW, p = pp % HW;
    int h = p / NW, w = p % NW;
    const float* ob = obs + (size_t)b*NCH*HW;
    float d = ob[3*HW + p];
    SplatCoord sc;
    compute_coord(d, h, w, fl, sc);
    if (!sem) {
        int cx = k & 1, cy = (k >> 1) & 1, cz = k >> 2;
        float wxv = cx ? sc.wx1 : sc.wx0;  int xiv = cx ? sc.xi1 : sc.xi0;
        float wyv = cy ? sc.wy1 : sc.wy0;  int yiv = cy ? sc.yi1 : sc.yi0;
        float wzv = cz ? sc.wz1 : sc.wz0;  int ziv = cz ? sc.zi1 : sc.zi0;
        float w3 = (wxv*wyv)*wzv;
        unsigned ywi = (unsigned)(yiv - YOFF);
        if (w3 != 0.0f && ywi < YW) {
            atomicAdd(&vox0[(((size_t)b*NZ + ziv)*YW + ywi)*VR + xiv], w3);
        }
    } else {
        float f0 = ob[(4+2*k)*HW + p];
        float f1 = ob[(5+2*k)*HW + p];
        #pragma unroll
        for (int cz = 0; cz < 2; cz++) {
            int z = cz ? sc.zi1 : sc.zi0;
            float wzv = cz ? sc.wz1 : sc.wz0;
            if (z < ZLO || z >= ZHI) continue;
            #pragma unroll
            for (int cy = 0; cy < 2; cy++) {
                float wyzv = (cy ? sc.wy1 : sc.wy0) * wzv;
                unsigned ywi = (unsigned)((cy ? sc.yi1 : sc.yi0) - YOFF);
                if (ywi >= YW) continue;
                #pragma unroll
                for (int cx = 0; cx < 2; cx++) {
                    float w3 = (cx ? sc.wx1 : sc.wx0) * wyzv;
                    int xiv = cx ? sc.xi1 : sc.xi0;
                    if (w3 == 0.0f) continue;
                    unsigned q0 = __float2uint_rn(f0*w3*QSCALE);
                    unsigned q1 = __float2uint_rn(f1*w3*QSCALE);
                    unsigned val = q0 | (q1 << 16);
                    if (val) {
                        size_t addr = (((((size_t)b*NZS + (z-ZLO))*YW + ywi)*VR + xiv)<<3) + k;
                        atomicAdd(&voxS[addr], val);
                    }
                }
            }
        }
    }
}

// ---------------- fused projections ----------------
// region A (t < NB*VR*VR): ch0 -> proj slots 0,1 + out0
// region B: sem halves, thread per (b,pixel,half): decode 8 packed channels -> proj slots 4+8h..
__global__ void proj_k(const float* __restrict__ vox0, const unsigned* __restrict__ voxS,
                       float* __restrict__ proj, float* __restrict__ out0) {
    int t = blockIdx.x*blockDim.x + threadIdx.x;
    if (t < NB*VR*VR) {
        int b = t / (VR*VR), r = t % (VR*VR);
        int yy = r / VR;
        float* pb = proj + ((size_t)b*(VR*VR) + r)*PC;
        if (yy < YOFF || yy >= YOFF+YW) {
            out0[(size_t)b*(VR*VR) + r] = 0.0f;
            *reinterpret_cast<float2*>(pb) = make_float2(0.0f, 0.0f);
            return;
        }
        int rw = (yy - YOFF)*VR + (r % VR);
        float s_all = 0.0f, s_slab = 0.0f;
        #pragma unroll 16
        for (int z = 0; z < NZ; z++) {
            float v = rintf(vox0[((size_t)b*NZ + z)*(YW*VR) + rw]);
            s_all += v;
            if (z >= ZLO && z < ZHI) s_slab += v;
        }
        float fpm = clamp01(s_slab);  // MAP_THR = 1
        float fpe = clamp01(s_all);   // EXP_THR = 1
        out0[(size_t)b*(VR*VR) + r] = fpm;
        *reinterpret_cast<float2*>(pb) = make_float2(fpm, fpe);
        return;
    }
    int t2 = t - NB*VR*VR;
    if (t2 >= NB*VR*VR*2) return;
    int hf = t2 & 1; int rr = t2 >> 1;
    int b = rr / (VR*VR), r = rr % (VR*VR);
    int yy = r / VR;
    float* dst = proj + ((size_t)b*(VR*VR) + r)*PC + 4 + hf*8;  // 16B aligned
    if (yy < YOFF || yy >= YOFF+YW) {
        *reinterpret_cast<float4*>(dst)     = make_float4(0.0f, 0.0f, 0.0f, 0.0f);
        *reinterpret_cast<float4*>(dst + 4) = make_float4(0.0f, 0.0f, 0.0f, 0.0f);
        return;
    }
    int rw = (yy - YOFF)*VR + (r % VR);
    float a0=0.f,a1=0.f,a2=0.f,a3=0.f,a4=0.f,a5=0.f,a6=0.f,a7=0.f;
    #pragma unroll 13
    for (int zs = 0; zs < NZS; zs++) {
        const uint4 v = *reinterpret_cast<const uint4*>(
            voxS + ((((size_t)b*NZS + zs)*(YW*VR) + rw)<<3) + hf*4);
        a0 += rintf((float)(v.x & 0xFFFFu)*QINV); a1 += rintf((float)(v.x >> 16)*QINV);
        a2 += rintf((float)(v.y & 0xFFFFu)*QINV); a3 += rintf((float)(v.y >> 16)*QINV);
        a4 += rintf((float)(v.z & 0xFFFFu)*QINV); a5 += rintf((float)(v.z >> 16)*QINV);
        a6 += rintf((float)(v.w & 0xFFFFu)*QINV); a7 += rintf((float)(v.w >> 16)*QINV);
    }
    *reinterpret_cast<float4*>(dst) = make_float4(
        clamp01(a0/5.0f), clamp01(a1/5.0f), clamp01(a2/5.0f), clamp01(a3/5.0f));
    *reinterpret_cast<float4*>(dst + 4) = make_float4(
        clamp01(a4/5.0f), clamp01(a5/5.0f), clamp01(a6/5.0f), clamp01(a7/5.0f));
}

// ---------------- fused rotate+translate + max, thread per (b,Y,X), all channels ----------------
__global__ void rottrans_k(const float* __restrict__ proj, const float* __restrict__ aux,
                           const float* __restrict__ maps, float* __restrict__ out1) {
    int t = blockIdx.x*blockDim.x + threadIdx.x;
    if (t >= NB*MD*MD) return;
    int X = t % MD; int rest = t / MD;
    int Y = rest % MD; int b = rest / MD;
    float ct = aux[b*4+0], st = aux[b*4+1];
    float tx = aux[b*4+2], ty = aux[b*4+3];
    const float step = 2.0f/239.0f;
    float Xg = (X == MD-1) ? 1.0f : (-1.0f + (float)X*step);
    float Yg = (Y == MD-1) ? 1.0f : (-1.0f + (float)Y*step);
    float x = (Xg + tx + 1.0f)*119.5f;
    float y = (Yg + ty + 1.0f)*119.5f;
    float x0 = floorf(x), y0 = floorf(y);

    int   toff[16];
    float twgt[16];
    #pragma unroll
    for (int tt = 0; tt < 4; tt++) {
        float ix = x0 + (float)(tt & 1);
        float iy = y0 + (float)(tt >> 1);
        float wt = ((tt & 1) ? (x - x0) : (x0 + 1.0f - x)) *
                   ((tt >> 1) ? (y - y0) : (y0 + 1.0f - y));
        bool tvalid = (ix >= 0.0f) && (ix < 240.0f) && (iy >= 0.0f) && (iy < 240.0f) && (wt != 0.0f);
        float u = 0.0f, v = 0.0f;
        if (tvalid) {
            int Xi = (int)ix, Yi = (int)iy;
            float Xg2 = (Xi == MD-1) ? 1.0f : (-1.0f + (float)Xi*step);
            float Yg2 = (Yi == MD-1) ? 1.0f : (-1.0f + (float)Yi*step);
            u = ct*Xg2 - st*Yg2;
            v = st*Xg2 + ct*Yg2;
        }
        float x2 = (u + 1.0f)*119.5f;
        float y2 = (v + 1.0f)*119.5f;
        float x20 = floorf(x2), y20 = floorf(y2);
        #pragma unroll
        for (int ii = 0; ii < 4; ii++) {
            float jx = x20 + (float)(ii & 1);
            float jy = y20 + (float)(ii >> 1);
            float w2 = ((ii & 1) ? (x2 - x20) : (x20 + 1.0f - x2)) *
                       ((ii >> 1) ? (y2 - y20) : (y20 + 1.0f - y2));
            bool ivalid = tvalid && (jy >= 120.0f) && (jy < 220.0f) && (jx >= 70.0f) && (jx < 170.0f);
            int slot = tt*4 + ii;
            twgt[slot] = ivalid ? wt * w2 : 0.0f;
            toff[slot] = ivalid ? (((int)jy - 120)*VR + ((int)jx - 70)) : 0;
        }
    }

    const float* pj = proj + (size_t)b*(VR*VR)*PC;
    float acc[PC];
    #pragma unroll
    for (int c = 0; c < PC; c++) acc[c] = 0.0f;
    #pragma unroll
    for (int s = 0; s < 16; s++) {
        float w = twgt[s];
        if (w == 0.0f) continue;
        const float* tp = pj + (size_t)toff[s]*PC;
        #pragma unroll
        for (int q = 0; q < 5; q++) {
            float4 v4 = *reinterpret_cast<const float4*>(tp + q*4);
            acc[q*4+0] += w*v4.x; acc[q*4+1] += w*v4.y;
            acc[q*4+2] += w*v4.z; acc[q*4+3] += w*v4.w;
        }
    }

    size_t obase = ((size_t)b*NCH)*(MD*MD) + (size_t)Y*MD + X;
    #pragma unroll
    for (int ch = 0; ch < NCH; ch++) {
        float m = maps[obase + (size_t)ch*(MD*MD)];
        float val = (ch == 2 || ch == 3) ? 0.0f : acc[ch];
        out1[obase + (size_t)ch*(MD*MD)] = fmaxf(m, val);
    }
}

extern "C" void kernel_launch(void* const* d_in, const int* in_sizes, int n_in,
                              void* d_out, int out_size, void* d_ws, size_t ws_size,
                              hipStream_t stream) {
    const float* obs        = (const float*)d_in[0];
    const float* pose_obs   = (const float*)d_in[1];
    const float* maps_last  = (const float*)d_in[2];
    const float* poses_last = (const float*)d_in[3];
    float* out  = (float*)d_out;
    float* out0 = out;                        // fp_map_pred: 8*1*100*100
    float* out1 = out + 80000;                // map_pred: 8*20*240*240
    float* out2 = out + 80000 + 9216000;      // poses
    float* out3 = out2 + 24;                  // poses (again)

    float*    ws   = (float*)d_ws;
    float*    vox0 = ws;                               // 8*80*64*100 f32        = 4,096,000
    unsigned* voxS = (unsigned*)(ws + 4096000);        // 8*26*64*100*8 u32      = 10,649,600
    float*    proj = ws + 4096000 + 10649600;          // 8*100*100*20 f32       = 1,600,000
    float*    aux  = ws + 4096000 + 10649600 + 1600000;  // 8*4

    const float FLf = (float)(80.0 / tan(39.5 * M_PI / 180.0));

    // zero the voxel accumulators (vox0 f32 + voxS u32, contiguous)
    hipMemsetAsync(vox0, 0, (size_t)(4096000 + 10649600)*sizeof(float), stream);
    pose_k    <<<1, 64, 0, stream>>>(pose_obs, poses_last, out2, out3, aux);
    splat_k   <<<(2*NB*HW*8 + 255)/256, 256, 0, stream>>>(obs, vox0, voxS, FLf);
    proj_k    <<<(3*NB*VR*VR + 255)/256, 256, 0, stream>>>(vox0, voxS, proj, out0);
    rottrans_k<<<(NB*MD*MD + 255)/256, 256, 0, stream>>>(proj, aux, maps_last, out1);
}

// Round 8
// 125.354 us; speedup vs baseline: 5.5369x; 1.0564x over previous
//
#include <hip/hip_runtime.h>
#include <math.h>

#define NB 8
#define NH 120
#define NW 160
#define HW (NH*NW)
#define NSEM 16
#define NCH 20
#define VR 100
#define NZ 80
#define NZP 40  // z stored as 40 u32 pairs of u16 fields (ch0)
#define ZLO 9
#define ZHI 35
#define NZS (ZHI-ZLO)
#define MD 240
#define PC 20   // proj channel stride (channel-innermost, slot == output channel, 2/3 unused)
#define YW 64   // y-window rows actually touchable by the splat (posy = d/5 in [10,70])
#define YOFF 8
#define QSCALE 1024.0f
#define QINV   0.0009765625f
#define QS0    256.0f
#define QS0INV 0.00390625f

__device__ __forceinline__ float clamp01(float v){ return fminf(fmaxf(v, 0.0f), 1.0f); }

// Scalar-field coordinate/weight computation (exact replica of reference f32 math).
// NO arrays: runtime-indexed arrays become allocas -> AMDGPUPromoteAlloca puts
// them in 48KB LDS (rounds 5/6: occupancy 27%, 3.4M LDS bank conflicts).
struct SplatCoord {
    float wx0, wx1, wy0, wy1, wz0, wz1;
    int   xi0, xi1, yi0, yi1, zi0, zi1;
};
__device__ __forceinline__ void compute_coord(float d, int h, int w, float fl, SplatCoord& sc) {
    float X = ((float)w - 79.5f) * d / fl;
    float Z = ((float)(119 - h) - 59.5f) * d / fl;
    float pcx = X + 250.0f;
    float pcy = d;
    float pcz = Z + 88.0f;
    float posx = ((pcx/5.0f - 50.0f)/100.0f*2.0f)*50.0f + 50.0f;
    float posy = ((pcy/5.0f - 50.0f)/100.0f*2.0f)*50.0f + 50.0f;
    float posz = ((pcz/5.0f - 32.0f)/80.0f*2.0f)*40.0f + 40.0f;
    float f;
    f = floorf(posx);
    { float pi = f;        bool s = (pi > 0.0f) && (pi < 100.0f);
      sc.wx0 = s ? (1.0f - fabsf(posx - pi)) : 0.0f; sc.xi0 = s ? (int)pi : 0; }
    { float pi = f + 1.0f; bool s = (pi > 0.0f) && (pi < 100.0f);
      sc.wx1 = s ? (1.0f - fabsf(posx - pi)) : 0.0f; sc.xi1 = s ? (int)pi : 0; }
    f = floorf(posy);
    { float pi = f;        bool s = (pi > 0.0f) && (pi < 100.0f);
      sc.wy0 = s ? (1.0f - fabsf(posy - pi)) : 0.0f; sc.yi0 = s ? (int)pi : 0; }
    { float pi = f + 1.0f; bool s = (pi > 0.0f) && (pi < 100.0f);
      sc.wy1 = s ? (1.0f - fabsf(posy - pi)) : 0.0f; sc.yi1 = s ? (int)pi : 0; }
    f = floorf(posz);
    { float pi = f;        bool s = (pi > 0.0f) && (pi < 80.0f);
      sc.wz0 = s ? (1.0f - fabsf(posz - pi)) : 0.0f; sc.zi0 = s ? (int)pi : 0; }
    { float pi = f + 1.0f; bool s = (pi > 0.0f) && (pi < 80.0f);
      sc.wz1 = s ? (1.0f - fabsf(posz - pi)) : 0.0f; sc.zi1 = s ? (int)pi : 0; }
}

// ---------------- pose + affine params ----------------
__global__ void pose_k(const float* __restrict__ pose_obs,
                       const float* __restrict__ poses_last,
                       float* __restrict__ out2, float* __restrict__ out3,
                       float* __restrict__ aux) {
    int b = threadIdx.x;
    if (b >= NB) return;
    const float D2R = 0.017453292519943295f;
    float th = poses_last[b*3+2] * D2R;
    float s = sinf(th), c = cosf(th);
    float ny = poses_last[b*3+1] + pose_obs[b*3+0]*s + pose_obs[b*3+1]*c;
    float nx = poses_last[b*3+0] + pose_obs[b*3+0]*c - pose_obs[b*3+1]*s;
    float nt = poses_last[b*3+2] + pose_obs[b*3+2]*57.29577951308232f;
    nt = fmodf(nt - 180.0f, 360.0f) + 180.0f;
    nt = fmodf(nt + 180.0f, 360.0f) - 180.0f;
    out2[b*3+0] = nx; out2[b*3+1] = ny; out2[b*3+2] = nt;
    out3[b*3+0] = nx; out3[b*3+1] = ny; out3[b*3+2] = nt;
    float stt = 90.0f - nt;
    float rad = stt * D2R;
    aux[b*4+0] = cosf(rad);
    aux[b*4+1] = sinf(rad);
    aux[b*4+2] = -(nx*100.0f/5.0f - 120.0f)/120.0f;  // st_xy[:,0]
    aux[b*4+3] = -(ny*100.0f/5.0f - 120.0f)/120.0f;  // st_xy[:,1]
}

// ---------------- ch0 splat: thread per (pixel, (cx,cy)) ----------------
// vox0q: [b][zp40][yw][x] u32, two u16 z-fields (scale 256). Even z0 -> one
// atomic covers both z-corners; cx-pair lanes 4B apart share L2 lines.
__global__ void splat0_k(const float* __restrict__ obs, unsigned* __restrict__ vox0q, float fl) {
    int t = blockIdx.x*blockDim.x + threadIdx.x;
    if (t >= NB*HW*4) return;
    int k = t & 3; int pp = t >> 2;
    int b = pp / HW, p = pp % HW;
    int h = p / NW, w = p % NW;
    float d = obs[((size_t)b*NCH + 3)*HW + p];
    SplatCoord sc;
    compute_coord(d, h, w, fl, sc);
    float wxy = ((k & 1) ? sc.wx1 : sc.wx0) * ((k >> 1) ? sc.wy1 : sc.wy0);
    int   xiv = (k & 1) ? sc.xi1 : sc.xi0;
    unsigned ywi = (unsigned)(((k >> 1) ? sc.yi1 : sc.yi0) - YOFF);
    if (wxy == 0.0f || ywi >= YW) return;
    unsigned q0 = __float2uint_rn(wxy*sc.wz0*QS0);
    unsigned q1 = __float2uint_rn(wxy*sc.wz1*QS0);
    if (!(q0 | q1)) return;
    int z0 = sc.zi0, z1 = sc.zi1;
    size_t rowcol = (size_t)ywi*VR + xiv;
    if (q0 && q1 && !(z0 & 1)) {
        // both valid => z1 == z0+1; z0 even => same u32 pair
        atomicAdd(&vox0q[((size_t)(b*NZP + (z0 >> 1))*YW*VR) + rowcol], q0 | (q1 << 16));
    } else {
        if (q0) atomicAdd(&vox0q[((size_t)(b*NZP + (z0 >> 1))*YW*VR) + rowcol],
                          (z0 & 1) ? (q0 << 16) : q0);
        if (q1) atomicAdd(&vox0q[((size_t)(b*NZP + (z1 >> 1))*YW*VR) + rowcol],
                          (z1 & 1) ? (q1 << 16) : q1);
    }
}

// ---------------- sem splat: thread per (pixel, channel-quad) ----------------
// voxS: [b][zs][yw][x][quad4] u64 = 4 x u16 fields (scale 1024). One u64 atomic
// updates 4 channels; no carry across fields (per-field sums << 2^16).
__global__ void splatS_k(const float* __restrict__ obs,
                         unsigned long long* __restrict__ voxS, float fl) {
    int t = blockIdx.x*blockDim.x + threadIdx.x;
    if (t >= NB*HW*4) return;
    int k = t & 3; int pp = t >> 2;
    int b = pp / HW, p = pp % HW;
    int h = p / NW, w = p % NW;
    const float* ob = obs + (size_t)b*NCH*HW;
    float d = ob[3*HW + p];
    SplatCoord sc;
    compute_coord(d, h, w, fl, sc);
    float f0 = ob[(4 + 4*k + 0)*HW + p];
    float f1 = ob[(4 + 4*k + 1)*HW + p];
    float f2 = ob[(4 + 4*k + 2)*HW + p];
    float f3 = ob[(4 + 4*k + 3)*HW + p];
    #pragma unroll
    for (int cz = 0; cz < 2; cz++) {
        int z = cz ? sc.zi1 : sc.zi0;
        float wzv = cz ? sc.wz1 : sc.wz0;
        if (z < ZLO || z >= ZHI) continue;
        #pragma unroll
        for (int cy = 0; cy < 2; cy++) {
            float wyz = (cy ? sc.wy1 : sc.wy0) * wzv;
            unsigned ywi = (unsigned)((cy ? sc.yi1 : sc.yi0) - YOFF);
            if (ywi >= YW) continue;
            #pragma unroll
            for (int cx = 0; cx < 2; cx++) {
                float w3 = (cx ? sc.wx1 : sc.wx0) * wyz;
                int xiv = cx ? sc.xi1 : sc.xi0;
                if (w3 == 0.0f) continue;
                unsigned q0 = __float2uint_rn(f0*w3*QSCALE);
                unsigned q1 = __float2uint_rn(f1*w3*QSCALE);
                unsigned q2 = __float2uint_rn(f2*w3*QSCALE);
                unsigned q3 = __float2uint_rn(f3*w3*QSCALE);
                unsigned long long val =
                    (unsigned long long)(q0 | (q1 << 16)) |
                    ((unsigned long long)(q2 | (q3 << 16)) << 32);
                if (val) {
                    size_t addr = (((((size_t)b*NZS + (z-ZLO))*YW + ywi)*VR + xiv)<<2) + k;
                    atomicAdd(&voxS[addr], val);
                }
            }
        }
    }
}

// ---------------- fused projections ----------------
// region A (t < NB*VR*VR): ch0 -> proj slots 0,1 + out0
// region B: sem halves, thread per (b,pixel,half): decode 8 packed channels -> proj slots 4+8h..
__global__ void proj_k(const unsigned* __restrict__ vox0q, const unsigned* __restrict__ voxS,
                       float* __restrict__ proj, float* __restrict__ out0) {
    int t = blockIdx.x*blockDim.x + threadIdx.x;
    if (t < NB*VR*VR) {
        int b = t / (VR*VR), r = t % (VR*VR);
        int yy = r / VR;
        float* pb = proj + ((size_t)b*(VR*VR) + r)*PC;
        if (yy < YOFF || yy >= YOFF+YW) {
            out0[(size_t)b*(VR*VR) + r] = 0.0f;
            *reinterpret_cast<float2*>(pb) = make_float2(0.0f, 0.0f);
            return;
        }
        int rw = (yy - YOFF)*VR + (r % VR);
        const unsigned* col = vox0q + (size_t)b*NZP*(YW*VR) + rw;
        float s_all = 0.0f, s_slab = 0.0f;
        #pragma unroll
        for (int zp = 0; zp < NZP; zp++) {
            unsigned v = col[(size_t)zp*(YW*VR)];
            float v0 = rintf((float)(v & 0xFFFFu)*QS0INV);  // z = 2*zp
            float v1 = rintf((float)(v >> 16)*QS0INV);      // z = 2*zp+1
            s_all += v0 + v1;
            if (zp >= 5 && zp <= 16) s_slab += v0 + v1;     // z 10..33
            else if (zp == 4) s_slab += v1;                 // z 9
            else if (zp == 17) s_slab += v0;                // z 34
        }
        float fpm = clamp01(s_slab);  // MAP_THR = 1
        float fpe = clamp01(s_all);   // EXP_THR = 1
        out0[(size_t)b*(VR*VR) + r] = fpm;
        *reinterpret_cast<float2*>(pb) = make_float2(fpm, fpe);
        return;
    }
    int t2 = t - NB*VR*VR;
    if (t2 >= NB*VR*VR*2) return;
    int hf = t2 & 1; int rr = t2 >> 1;
    int b = rr / (VR*VR), r = rr % (VR*VR);
    int yy = r / VR;
    float* dst = proj + ((size_t)b*(VR*VR) + r)*PC + 4 + hf*8;  // 16B aligned
    if (yy < YOFF || yy >= YOFF+YW) {
        *reinterpret_cast<float4*>(dst)     = make_float4(0.0f, 0.0f, 0.0f, 0.0f);
        *reinterpret_cast<float4*>(dst + 4) = make_float4(0.0f, 0.0f, 0.0f, 0.0f);
        return;
    }
    int rw = (yy - YOFF)*VR + (r % VR);
    float a0=0.f,a1=0.f,a2=0.f,a3=0.f,a4=0.f,a5=0.f,a6=0.f,a7=0.f;
    #pragma unroll 13
    for (int zs = 0; zs < NZS; zs++) {
        const uint4 v = *reinterpret_cast<const uint4*>(
            voxS + ((((size_t)b*NZS + zs)*(YW*VR) + rw)<<3) + hf*4);
        a0 += rintf((float)(v.x & 0xFFFFu)*QINV); a1 += rintf((float)(v.x >> 16)*QINV);
        a2 += rintf((float)(v.y & 0xFFFFu)*QINV); a3 += rintf((float)(v.y >> 16)*QINV);
        a4 += rintf((float)(v.z & 0xFFFFu)*QINV); a5 += rintf((float)(v.z >> 16)*QINV);
        a6 += rintf((float)(v.w & 0xFFFFu)*QINV); a7 += rintf((float)(v.w >> 16)*QINV);
    }
    *reinterpret_cast<float4*>(dst) = make_float4(
        clamp01(a0/5.0f), clamp01(a1/5.0f), clamp01(a2/5.0f), clamp01(a3/5.0f));
    *reinterpret_cast<float4*>(dst + 4) = make_float4(
        clamp01(a4/5.0f), clamp01(a5/5.0f), clamp01(a6/5.0f), clamp01(a7/5.0f));
}

// ---------------- fused rotate+translate + max, thread per (b,Y,X), all channels ----------------
__global__ void rottrans_k(const float* __restrict__ proj, const float* __restrict__ aux,
                           const float* __restrict__ maps, float* __restrict__ out1) {
    int t = blockIdx.x*blockDim.x + threadIdx.x;
    if (t >= NB*MD*MD) return;
    int X = t % MD; int rest = t / MD;
    int Y = rest % MD; int b = rest / MD;
    float ct = aux[b*4+0], st = aux[b*4+1];
    float tx = aux[b*4+2], ty = aux[b*4+3];
    const float step = 2.0f/239.0f;
    float Xg = (X == MD-1) ? 1.0f : (-1.0f + (float)X*step);
    float Yg = (Y == MD-1) ? 1.0f : (-1.0f + (float)Y*step);
    float x = (Xg + tx + 1.0f)*119.5f;
    float y = (Yg + ty + 1.0f)*119.5f;
    float x0 = floorf(x), y0 = floorf(y);

    int   toff[16];
    float twgt[16];
    #pragma unroll
    for (int tt = 0; tt < 4; tt++) {
        float ix = x0 + (float)(tt & 1);
        float iy = y0 + (float)(tt >> 1);
        float wt = ((tt & 1) ? (x - x0) : (x0 + 1.0f - x)) *
                   ((tt >> 1) ? (y - y0) : (y0 + 1.0f - y));
        bool tvalid = (ix >= 0.0f) && (ix < 240.0f) && (iy >= 0.0f) && (iy < 240.0f) && (wt != 0.0f);
        float u = 0.0f, v = 0.0f;
        if (tvalid) {
            int Xi = (int)ix, Yi = (int)iy;
            float Xg2 = (Xi == MD-1) ? 1.0f : (-1.0f + (float)Xi*step);
            float Yg2 = (Yi == MD-1) ? 1.0f : (-1.0f + (float)Yi*step);
            u = ct*Xg2 - st*Yg2;
            v = st*Xg2 + ct*Yg2;
        }
        float x2 = (u + 1.0f)*119.5f;
        float y2 = (v + 1.0f)*119.5f;
        float x20 = floorf(x2), y20 = floorf(y2);
        #pragma unroll
        for (int ii = 0; ii < 4; ii++) {
            float jx = x20 + (float)(ii & 1);
            float jy = y20 + (float)(ii >> 1);
            float w2 = ((ii & 1) ? (x2 - x20) : (x20 + 1.0f - x2)) *
                       ((ii >> 1) ? (y2 - y20) : (y20 + 1.0f - y2));
            bool ivalid = tvalid && (jy >= 120.0f) && (jy < 220.0f) && (jx >= 70.0f) && (jx < 170.0f);
            int slot = tt*4 + ii;
            twgt[slot] = ivalid ? wt * w2 : 0.0f;
            toff[slot] = ivalid ? (((int)jy - 120)*VR + ((int)jx - 70)) : 0;
        }
    }

    const float* pj = proj + (size_t)b*(VR*VR)*PC;
    float acc[PC];
    #pragma unroll
    for (int c = 0; c < PC; c++) acc[c] = 0.0f;
    #pragma unroll
    for (int s = 0; s < 16; s++) {
        float w = twgt[s];
        if (w == 0.0f) continue;
        const float* tp = pj + (size_t)toff[s]*PC;
        #pragma unroll
        for (int q = 0; q < 5; q++) {
            float4 v4 = *reinterpret_cast<const float4*>(tp + q*4);
            acc[q*4+0] += w*v4.x; acc[q*4+1] += w*v4.y;
            acc[q*4+2] += w*v4.z; acc[q*4+3] += w*v4.w;
        }
    }

    size_t obase = ((size_t)b*NCH)*(MD*MD) + (size_t)Y*MD + X;
    #pragma unroll
    for (int ch = 0; ch < NCH; ch++) {
        float m = maps[obase + (size_t)ch*(MD*MD)];
        float val = (ch == 2 || ch == 3) ? 0.0f : acc[ch];
        out1[obase + (size_t)ch*(MD*MD)] = fmaxf(m, val);
    }
}

extern "C" void kernel_launch(void* const* d_in, const int* in_sizes, int n_in,
                              void* d_out, int out_size, void* d_ws, size_t ws_size,
                              hipStream_t stream) {
    const float* obs        = (const float*)d_in[0];
    const float* pose_obs   = (const float*)d_in[1];
    const float* maps_last  = (const float*)d_in[2];
    const float* poses_last = (const float*)d_in[3];
    float* out  = (float*)d_out;
    float* out0 = out;                        // fp_map_pred: 8*1*100*100
    float* out1 = out + 80000;                // map_pred: 8*20*240*240
    float* out2 = out + 80000 + 9216000;      // poses
    float* out3 = out2 + 24;                  // poses (again)

    unsigned*           vox0q = (unsigned*)d_ws;                       // 8*40*64*100 u32 = 2,048,000
    unsigned long long* voxS  = (unsigned long long*)((float*)d_ws + 2048000); // 5,324,800 u64 (8B-aligned)
    float*              proj  = (float*)d_ws + 2048000 + 10649600;     // 8*100*100*20 f32
    float*              aux   = proj + 1600000;                        // 8*4

    const float FLf = (float)(80.0 / tan(39.5 * M_PI / 180.0));

    // zero the voxel accumulators (vox0q + voxS, contiguous: 50.8 MB)
    hipMemsetAsync(vox0q, 0, (size_t)(2048000 + 10649600)*4, stream);
    pose_k    <<<1, 64, 0, stream>>>(pose_obs, poses_last, out2, out3, aux);
    splat0_k  <<<(NB*HW*4 + 255)/256, 256, 0, stream>>>(obs, vox0q, FLf);
    splatS_k  <<<(NB*HW*4 + 255)/256, 256, 0, stream>>>(obs, voxS, FLf);
    proj_k    <<<(3*NB*VR*VR + 255)/256, 256, 0, stream>>>(vox0q, (const unsigned*)voxS, proj, out0);
    rottrans_k<<<(NB*MD*MD + 255)/256, 256, 0, stream>>>(proj, aux, maps_last, out1);
}